// Round 1
// baseline (571.860 us; speedup 1.0000x reference)
//
#include <hip/hip_runtime.h>
#include <hip/hip_bf16.h>

#define UN 2048
#define SN 8192
#define NA 10240
#define DN 128

typedef __attribute__((ext_vector_type(8))) short bf16x8;
typedef __attribute__((ext_vector_type(4))) float f32x4;

__device__ __forceinline__ unsigned short f2bf(float f) {
  unsigned int u = __builtin_bit_cast(unsigned int, f);
  u += 0x7fffu + ((u >> 16) & 1u);
  return (unsigned short)(u >> 16);
}
__device__ __forceinline__ unsigned int pk2(float a, float b) {
  return (unsigned int)f2bf(a) | ((unsigned int)f2bf(b) << 16);
}
__device__ __forceinline__ float4 f4add(float4 a, float4 b) {
  return make_float4(a.x + b.x, a.y + b.y, a.z + b.z, a.w + b.w);
}
// LDS helpers with XOR swizzle (G4: break 128B-stride bank conflicts).
__device__ __forceinline__ void st16(unsigned char* base, int row, int cb, int stride, uint4 v) {
  int off = row * stride + cb;
  off ^= (row & 7) << 4;
  *(uint4*)(base + off) = v;
}
__device__ __forceinline__ bf16x8 ld16(const unsigned char* base, int row, int cb, int stride) {
  int off = row * stride + cb;
  off ^= (row & 7) << 4;
  return *(const bf16x8*)(base + off);
}
__device__ __forceinline__ void st2(unsigned char* base, int row, int cb, int stride, unsigned short h) {
  int off = row * stride + cb;
  off ^= (row & 7) << 4;
  *(unsigned short*)(base + off) = h;
}

// all_emb = concat(user_emb, item_emb); embs_sum = all_emb
__global__ void k_init(const float4* __restrict__ ue, const float4* __restrict__ ie,
                       float4* __restrict__ ae, float4* __restrict__ es) {
  int i = blockIdx.x * 256 + threadIdx.x;  // over NA*DN/4 = 327680 float4
  float4 v = (i < UN * DN / 4) ? ue[i] : ie[i - UN * DN / 4];
  ae[i] = v;
  es[i] = v;
}

// Bt[c][r] = bf16(x[r][c]); tiled transpose via LDS
__global__ void k_bt(const float* __restrict__ x, unsigned short* __restrict__ bt) {
  __shared__ float tile[32][33];
  const int tr = blockIdx.x;  // 0..319
  const int tc = blockIdx.y;  // 0..3
  const int lr = threadIdx.x / 32, lc = threadIdx.x % 32;
#pragma unroll
  for (int i = 0; i < 4; i++)
    tile[lr + i * 8][lc] = x[(size_t)(tr * 32 + lr + i * 8) * DN + tc * 32 + lc];
  __syncthreads();
#pragma unroll
  for (int i = 0; i < 4; i++)
    bt[(size_t)(tc * 32 + lr + i * 8) * NA + tr * 32 + lc] = f2bf(tile[lc][lr + i * 8]);
}

// part[ks] = grpha[:, ks-chunk] @ Bt[ks-chunk]^T  (M=10240,N=128,K=2560 per split)
__global__ __launch_bounds__(256) void k_gemm(const float* __restrict__ A,
                                              const unsigned short* __restrict__ Bt,
                                              float* __restrict__ part) {
  __shared__ unsigned char As[64 * 64 * 2];    // 8 KB  [64 m][64 k] bf16, swizzled
  __shared__ unsigned char Bs[128 * 64 * 2];   // 16 KB [128 n][64 k] bf16, swizzled
  const int ks = blockIdx.x;
  const int m0 = blockIdx.y * 64;
  const int k0 = ks * (NA / 4);
  const int tid = threadIdx.x;
  const int wave = tid >> 6, lane = tid & 63;
  const int lrow = lane & 15;
  const int kgrp = (lane >> 4) * 8;
  const int wr = wave * 16;
  const int arow = tid >> 2, acol = (tid & 3) * 16;
  const int brow = tid >> 1, bcol = (tid & 1) * 32;

  f32x4 acc[8];
#pragma unroll
  for (int i = 0; i < 8; i++) acc[i] = (f32x4){0.f, 0.f, 0.f, 0.f};

  for (int kt = 0; kt < (NA / 4) / 64; kt++) {
    const int kg = k0 + kt * 64;
    const float4* ag = (const float4*)(A + (size_t)(m0 + arow) * NA + kg + acol);
    float4 a0 = ag[0], a1 = ag[1], a2 = ag[2], a3 = ag[3];
    const uint4* bg = (const uint4*)(Bt + (size_t)brow * NA + kg + bcol);
    uint4 b0 = bg[0], b1 = bg[1], b2 = bg[2], b3 = bg[3];

    __syncthreads();  // prior compute done before overwrite
    uint4 wA0, wA1;
    wA0.x = pk2(a0.x, a0.y); wA0.y = pk2(a0.z, a0.w);
    wA0.z = pk2(a1.x, a1.y); wA0.w = pk2(a1.z, a1.w);
    wA1.x = pk2(a2.x, a2.y); wA1.y = pk2(a2.z, a2.w);
    wA1.z = pk2(a3.x, a3.y); wA1.w = pk2(a3.z, a3.w);
    st16(As, arow, acol * 2, 128, wA0);
    st16(As, arow, acol * 2 + 16, 128, wA1);
    st16(Bs, brow, bcol * 2, 128, b0);
    st16(Bs, brow, bcol * 2 + 16, 128, b1);
    st16(Bs, brow, bcol * 2 + 32, 128, b2);
    st16(Bs, brow, bcol * 2 + 48, 128, b3);
    __syncthreads();

#pragma unroll
    for (int kk = 0; kk < 64; kk += 32) {
      bf16x8 af = ld16(As, wr + lrow, (kk + kgrp) * 2, 128);
#pragma unroll
      for (int ct = 0; ct < 8; ct++) {
        bf16x8 bf = ld16(Bs, ct * 16 + lrow, (kk + kgrp) * 2, 128);
        acc[ct] = __builtin_amdgcn_mfma_f32_16x16x32_bf16(af, bf, acc[ct], 0, 0, 0);
      }
    }
  }

  float* op = part + (size_t)ks * NA * DN;
  const int orow = m0 + wr + (lane >> 4) * 4;
#pragma unroll
  for (int ct = 0; ct < 8; ct++)
#pragma unroll
    for (int i = 0; i < 4; i++)
      op[(size_t)(orow + i) * DN + ct * 16 + lrow] = acc[ct][i];
}

// x = (sum of 4 partials)*scale; x=leaky(x@W1^T+b1); x=leaky(x@W2^T+b2); x=x@W3^T+b3;
// all_emb = x; embs_sum += x
__global__ __launch_bounds__(256) void k_transform(
    const float* __restrict__ part, float scale,
    const float* __restrict__ W1, const float* __restrict__ b1,
    const float* __restrict__ W2, const float* __restrict__ b2,
    const float* __restrict__ W3, const float* __restrict__ b3,
    float* __restrict__ all_emb, float* __restrict__ embs_sum) {
  __shared__ unsigned char Ws[128 * 128 * 2];  // 32 KB
  __shared__ unsigned char Xa[64 * 128 * 2];   // 16 KB
  __shared__ unsigned char Xb[64 * 128 * 2];   // 16 KB
  const int r0 = blockIdx.x * 64;
  const int tid = threadIdx.x;
  const int wave = tid >> 6, lane = tid & 63;
  const int lrow = lane & 15;
  const int kgrp = (lane >> 4) * 8;
  const int wr = wave * 16;

  {  // stage input tile into Xa (bf16, swizzled)
    const int xr = tid >> 2, xc = (tid & 3) * 32;
    const size_t base = (size_t)(r0 + xr) * DN + xc;
    const float4* p0 = (const float4*)(part + base);
    const float4* p1 = (const float4*)(part + (size_t)NA * DN + base);
    const float4* p2 = (const float4*)(part + 2 * (size_t)NA * DN + base);
    const float4* p3 = (const float4*)(part + 3 * (size_t)NA * DN + base);
#pragma unroll
    for (int j = 0; j < 4; j++) {
      float4 u = f4add(f4add(p0[2 * j], p1[2 * j]), f4add(p2[2 * j], p3[2 * j]));
      float4 v = f4add(f4add(p0[2 * j + 1], p1[2 * j + 1]), f4add(p2[2 * j + 1], p3[2 * j + 1]));
      uint4 w;
      w.x = pk2(u.x * scale, u.y * scale); w.y = pk2(u.z * scale, u.w * scale);
      w.z = pk2(v.x * scale, v.y * scale); w.w = pk2(v.z * scale, v.w * scale);
      st16(Xa, xr, (xc + j * 8) * 2, 256, w);
    }
  }

  const float* Wp[3] = {W1, W2, W3};
  const float* bp[3] = {b1, b2, b3};
  unsigned char* Xin = Xa;
  unsigned char* Xout = Xb;
  const int wrow = tid >> 1, wc = (tid & 1) * 64;

  for (int s = 0; s < 3; s++) {
    float4 wv[16];
    const float4* wg = (const float4*)(Wp[s] + (size_t)wrow * DN + wc);
#pragma unroll
    for (int j = 0; j < 16; j++) wv[j] = wg[j];
    float bb[8];
#pragma unroll
    for (int ct = 0; ct < 8; ct++) bb[ct] = bp[s][ct * 16 + lrow];

    __syncthreads();  // prior stage's reads (Ws, Xin) and writes (Xout) complete
#pragma unroll
    for (int j = 0; j < 8; j++) {
      uint4 w;
      w.x = pk2(wv[2 * j].x, wv[2 * j].y);         w.y = pk2(wv[2 * j].z, wv[2 * j].w);
      w.z = pk2(wv[2 * j + 1].x, wv[2 * j + 1].y); w.w = pk2(wv[2 * j + 1].z, wv[2 * j + 1].w);
      st16(Ws, wrow, (wc + j * 8) * 2, 256, w);
    }
    __syncthreads();

    f32x4 acc[8];
#pragma unroll
    for (int i = 0; i < 8; i++) acc[i] = (f32x4){0.f, 0.f, 0.f, 0.f};
#pragma unroll
    for (int kk = 0; kk < 128; kk += 32) {
      bf16x8 af = ld16(Xin, wr + lrow, (kk + kgrp) * 2, 256);
#pragma unroll
      for (int ct = 0; ct < 8; ct++) {
        bf16x8 bf = ld16(Ws, ct * 16 + lrow, (kk + kgrp) * 2, 256);
        acc[ct] = __builtin_amdgcn_mfma_f32_16x16x32_bf16(af, bf, acc[ct], 0, 0, 0);
      }
    }

    if (s < 2) {
#pragma unroll
      for (int ct = 0; ct < 8; ct++)
#pragma unroll
        for (int i = 0; i < 4; i++) {
          int row = wr + (lane >> 4) * 4 + i;
          int col = ct * 16 + lrow;
          float v = acc[ct][i] + bb[ct];
          v = v > 0.f ? v : 0.01f * v;
          st2(Xout, row, col * 2, 256, f2bf(v));
        }
      unsigned char* t = Xin; Xin = Xout; Xout = t;
    } else {
#pragma unroll
      for (int ct = 0; ct < 8; ct++)
#pragma unroll
        for (int i = 0; i < 4; i++) {
          int row = wr + (lane >> 4) * 4 + i;
          int col = ct * 16 + lrow;
          float v = acc[ct][i] + bb[ct];
          size_t gi = (size_t)(r0 + row) * DN + col;
          all_emb[gi] = v;
          embs_sum[gi] += v;
        }
    }
  }
}

// embs_sum (fp32) -> bf16, same layout
__global__ void k_cvt(const float* __restrict__ x, unsigned short* __restrict__ y) {
  int i = blockIdx.x * 256 + threadIdx.x;  // per 8 elements
  const float4* p = (const float4*)(x + (size_t)i * 8);
  float4 a = p[0], b = p[1];
  uint4 w;
  w.x = pk2(a.x, a.y); w.y = pk2(a.z, a.w);
  w.z = pk2(b.x, b.y); w.w = pk2(b.z, b.w);
  ((uint4*)y)[i] = w;
}

// fused: pre = (users@items^T)*mask; partial[blk] = sum(w*|pre - tq|) over 32x128 tile
__global__ __launch_bounds__(256) void k_loss(const unsigned short* __restrict__ sbf,
                                              const float* __restrict__ tq,
                                              const float* __restrict__ lw,
                                              const int* __restrict__ msk,
                                              float* __restrict__ partial) {
  const unsigned short* ubf = sbf;
  const unsigned short* ibf = sbf + (size_t)UN * DN;
  const int r0 = blockIdx.x * 32;
  const int c0 = blockIdx.y * 128;
  const int tid = threadIdx.x;
  const int wave = tid >> 6, lane = tid & 63;
  const int wr = (wave >> 1) * 16;
  const int wc = (wave & 1) * 64;
  const int lrow = lane & 15;
  const int kgrp = (lane >> 4) * 8;

  f32x4 acc[4];
#pragma unroll
  for (int i = 0; i < 4; i++) acc[i] = (f32x4){0.f, 0.f, 0.f, 0.f};
#pragma unroll
  for (int kk = 0; kk < 128; kk += 32) {
    bf16x8 af = *(const bf16x8*)(ubf + (size_t)(r0 + wr + lrow) * DN + kk + kgrp);
#pragma unroll
    for (int ct = 0; ct < 4; ct++) {
      bf16x8 bf = *(const bf16x8*)(ibf + (size_t)(c0 + wc + ct * 16 + lrow) * DN + kk + kgrp);
      acc[ct] = __builtin_amdgcn_mfma_f32_16x16x32_bf16(af, bf, acc[ct], 0, 0, 0);
    }
  }
  float lsum = 0.f;
#pragma unroll
  for (int ct = 0; ct < 4; ct++)
#pragma unroll
    for (int i = 0; i < 4; i++) {
      int r = r0 + wr + (lane >> 4) * 4 + i;
      int c = c0 + wc + ct * 16 + lrow;
      size_t gi = (size_t)r * SN + c;
      float pre = msk[gi] ? acc[ct][i] : 0.f;
      lsum += lw[gi] * fabsf(pre - tq[gi]);
    }
  __shared__ float red[256];
  red[tid] = lsum;
  __syncthreads();
  for (int st = 128; st > 0; st >>= 1) {
    if (tid < st) red[tid] += red[tid + st];
    __syncthreads();
  }
  if (tid == 0) partial[blockIdx.x * 64 + blockIdx.y] = red[0];
}

__global__ void k_reduce(const float* __restrict__ p, float* __restrict__ out) {
  __shared__ float red[256];
  float s = 0.f;
  for (int i = threadIdx.x; i < 4096; i += 256) s += p[i];
  red[threadIdx.x] = s;
  __syncthreads();
  for (int st = 128; st > 0; st >>= 1) {
    if (threadIdx.x < st) red[threadIdx.x] += red[threadIdx.x + st];
    __syncthreads();
  }
  if (threadIdx.x == 0) out[0] = red[0];
}

extern "C" void kernel_launch(void* const* d_in, const int* in_sizes, int n_in,
                              void* d_out, int out_size, void* d_ws, size_t ws_size,
                              hipStream_t stream) {
  const float* user_emb = (const float*)d_in[0];
  const float* item_emb = (const float*)d_in[1];
  const float* grpha    = (const float*)d_in[2];
  const float* W1 = (const float*)d_in[3];
  const float* b1 = (const float*)d_in[4];
  const float* W2 = (const float*)d_in[5];
  const float* b2 = (const float*)d_in[6];
  const float* W3 = (const float*)d_in[7];
  const float* b3 = (const float*)d_in[8];
  const float* tq = (const float*)d_in[9];
  const float* lw = (const float*)d_in[10];
  const int* msk  = (const int*)d_in[11];
  float* out = (float*)d_out;

  char* ws = (char*)d_ws;
  float* all_emb  = (float*)ws;          ws += (size_t)NA * DN * 4;
  float* embs_sum = (float*)ws;          ws += (size_t)NA * DN * 4;
  float* part     = (float*)ws;          ws += (size_t)4 * NA * DN * 4;
  unsigned short* Bt  = (unsigned short*)ws; ws += (size_t)NA * DN * 2;
  unsigned short* sbf = (unsigned short*)ws; ws += (size_t)NA * DN * 2;
  float* lpart    = (float*)ws;          ws += 4096 * 4;

  k_init<<<1280, 256, 0, stream>>>((const float4*)user_emb, (const float4*)item_emb,
                                   (float4*)all_emb, (float4*)embs_sum);
  for (int layer = 0; layer < 3; layer++) {
    k_bt<<<dim3(320, 4), 256, 0, stream>>>(all_emb, Bt);
    k_gemm<<<dim3(4, 160), 256, 0, stream>>>(grpha, Bt, part);
    k_transform<<<160, 256, 0, stream>>>(part, 1.0f / (1.0f + (float)layer),
                                         W1, b1, W2, b2, W3, b3, all_emb, embs_sum);
  }
  k_cvt<<<640, 256, 0, stream>>>(embs_sum, sbf);
  k_loss<<<dim3(64, 64), 256, 0, stream>>>(sbf, tq, lw, msk, lpart);
  k_reduce<<<1, 256, 0, stream>>>(lpart, out);
}

// Round 2
// 511.625 us; speedup vs baseline: 1.1177x; 1.1177x over previous
//
#include <hip/hip_runtime.h>
#include <hip/hip_bf16.h>

#define UN 2048
#define SN 8192
#define NA 10240
#define DN 128
#define SPLITS 8
#define KSPL (NA / SPLITS)  // 1280
#define BK 64
#define KT (KSPL / BK)      // 20

typedef __attribute__((ext_vector_type(8))) short bf16x8;
typedef __attribute__((ext_vector_type(4))) float f32x4;

__device__ __forceinline__ unsigned short f2bf(float f) {
  unsigned int u = __builtin_bit_cast(unsigned int, f);
  u += 0x7fffu + ((u >> 16) & 1u);
  return (unsigned short)(u >> 16);
}
__device__ __forceinline__ unsigned int pk2(float a, float b) {
  return (unsigned int)f2bf(a) | ((unsigned int)f2bf(b) << 16);
}
__device__ __forceinline__ float4 f4add(float4 a, float4 b) {
  return make_float4(a.x + b.x, a.y + b.y, a.z + b.z, a.w + b.w);
}
// async global->LDS, 16B per lane (dest = wave-uniform base + lane*16)
__device__ __forceinline__ void gl_lds16(const void* g, void* l) {
  __builtin_amdgcn_global_load_lds((const __attribute__((address_space(1))) unsigned int*)g,
                                   (__attribute__((address_space(3))) unsigned int*)l, 16, 0, 0);
}
// swizzled LDS helpers for fp32->bf16 staged tiles (k_transform)
__device__ __forceinline__ void st16(unsigned char* base, int row, int cb, int stride, uint4 v) {
  int off = row * stride + cb;
  off ^= (row & 7) << 4;
  *(uint4*)(base + off) = v;
}
__device__ __forceinline__ bf16x8 ld16(const unsigned char* base, int row, int cb, int stride) {
  int off = row * stride + cb;
  off ^= (row & 7) << 4;
  return *(const bf16x8*)(base + off);
}
__device__ __forceinline__ void st2(unsigned char* base, int row, int cb, int stride, unsigned short h) {
  int off = row * stride + cb;
  off ^= (row & 7) << 4;
  *(unsigned short*)(base + off) = h;
}

// all_emb = concat(user_emb, item_emb); embs_sum = all_emb
__global__ void k_init(const float4* __restrict__ ue, const float4* __restrict__ ie,
                       float4* __restrict__ ae, float4* __restrict__ es) {
  int i = blockIdx.x * 256 + threadIdx.x;
  float4 v = (i < UN * DN / 4) ? ue[i] : ie[i - UN * DN / 4];
  ae[i] = v;
  es[i] = v;
}

// Bt[c][r] = bf16(x[r][c]); tiled transpose via LDS
__global__ void k_bt(const float* __restrict__ x, unsigned short* __restrict__ bt) {
  __shared__ float tile[32][33];
  const int tr = blockIdx.x;  // 0..319
  const int tc = blockIdx.y;  // 0..3
  const int lr = threadIdx.x / 32, lc = threadIdx.x % 32;
#pragma unroll
  for (int i = 0; i < 4; i++)
    tile[lr + i * 8][lc] = x[(size_t)(tr * 32 + lr + i * 8) * DN + tc * 32 + lc];
  __syncthreads();
#pragma unroll
  for (int i = 0; i < 4; i++)
    bt[(size_t)(tc * 32 + lr + i * 8) * NA + tr * 32 + lc] = f2bf(tile[lc][lr + i * 8]);
}

// fp32 -> bf16 stream (8 elems/thread); used for grpha (once) and embs_sum
__global__ void k_cvt(const float* __restrict__ x, unsigned short* __restrict__ y) {
  size_t i = (size_t)blockIdx.x * 256 + threadIdx.x;
  const float4* p = (const float4*)(x + i * 8);
  float4 a = p[0], b = p[1];
  uint4 w;
  w.x = pk2(a.x, a.y); w.y = pk2(a.z, a.w);
  w.z = pk2(b.x, b.y); w.w = pk2(b.z, b.w);
  ((uint4*)y)[i] = w;
}

// part[ks] = A_bf16[:, ks-chunk] @ Bt[ks-chunk]^T
// m97 structure: BM=128, BN=128, BK=64, global_load_lds w16, pre-swizzled source.
__global__ __launch_bounds__(256) void k_gemm(const unsigned short* __restrict__ A,
                                              const unsigned short* __restrict__ Bt,
                                              float* __restrict__ part) {
  __shared__ unsigned short As[128 * 64];  // 16 KB, [row][k] rows=128B, chunk-XOR swizzled
  __shared__ unsigned short Bs[128 * 64];  // 16 KB
  const int ks = blockIdx.x;
  const int m0 = blockIdx.y * 128;
  const int k0 = ks * KSPL;
  const int tid = threadIdx.x;
  const int wave = tid >> 6, lane = tid & 63;
  const int lrow = lane & 15;
  const int kq = lane >> 4;          // k-chunk sub-index (0..3)
  const int wr = (wave >> 1) * 64;   // wave row base
  const int wc = (wave & 1) * 64;    // wave col base

  f32x4 acc[4][4];
#pragma unroll
  for (int fi = 0; fi < 4; fi++)
#pragma unroll
    for (int fj = 0; fj < 4; fj++) acc[fi][fj] = (f32x4){0.f, 0.f, 0.f, 0.f};

  for (int kt = 0; kt < KT; kt++) {
    const int kg = k0 + kt * BK;
    // stage: linear LDS dest, inverse-swizzled global source (both-sides rule)
#pragma unroll
    for (int j = 0; j < 4; j++) {
      const int L = j * 256 + tid;
      const int row = L >> 3, c = L & 7;
      const int sc = (c ^ (row & 7)) << 3;  // swizzled chunk, in elements
      gl_lds16(A + (size_t)(m0 + row) * NA + kg + sc, (char*)As + L * 16);
      gl_lds16(Bt + (size_t)row * NA + kg + sc, (char*)Bs + L * 16);
    }
    __syncthreads();  // compiler drains vmcnt(0) before s_barrier: tile ready

#pragma unroll
    for (int ks2 = 0; ks2 < 2; ks2++) {
      const int kc = ks2 * 4 + kq;
      bf16x8 av[4], bv[4];
#pragma unroll
      for (int fi = 0; fi < 4; fi++) {
        const int row = wr + fi * 16 + lrow;
        av[fi] = *(const bf16x8*)((const char*)As + row * 128 + ((kc ^ (row & 7)) << 4));
      }
#pragma unroll
      for (int fj = 0; fj < 4; fj++) {
        const int row = wc + fj * 16 + lrow;
        bv[fj] = *(const bf16x8*)((const char*)Bs + row * 128 + ((kc ^ (row & 7)) << 4));
      }
#pragma unroll
      for (int fi = 0; fi < 4; fi++)
#pragma unroll
        for (int fj = 0; fj < 4; fj++)
          acc[fi][fj] = __builtin_amdgcn_mfma_f32_16x16x32_bf16(av[fi], bv[fj], acc[fi][fj], 0, 0, 0);
    }
    __syncthreads();  // all reads done before next stage overwrites
  }

  float* op = part + (size_t)ks * NA * DN;
#pragma unroll
  for (int fi = 0; fi < 4; fi++) {
    const int row0 = m0 + wr + fi * 16 + kq * 4;
#pragma unroll
    for (int fj = 0; fj < 4; fj++) {
      const int col = wc + fj * 16 + lrow;
#pragma unroll
      for (int i = 0; i < 4; i++)
        op[(size_t)(row0 + i) * DN + col] = acc[fi][fj][i];
    }
  }
}

// x = (sum of SPLITS partials)*scale; 3-layer MLP; all_emb = x; embs_sum += x
__global__ __launch_bounds__(256) void k_transform(
    const float* __restrict__ part, float scale,
    const float* __restrict__ W1, const float* __restrict__ b1,
    const float* __restrict__ W2, const float* __restrict__ b2,
    const float* __restrict__ W3, const float* __restrict__ b3,
    float* __restrict__ all_emb, float* __restrict__ embs_sum) {
  __shared__ unsigned char Ws[128 * 128 * 2];  // 32 KB
  __shared__ unsigned char Xa[64 * 128 * 2];   // 16 KB
  __shared__ unsigned char Xb[64 * 128 * 2];   // 16 KB
  const int r0 = blockIdx.x * 64;
  const int tid = threadIdx.x;
  const int wave = tid >> 6, lane = tid & 63;
  const int lrow = lane & 15;
  const int kgrp = (lane >> 4) * 8;
  const int wr = wave * 16;

  {  // stage input tile into Xa (bf16, swizzled)
    const int xr = tid >> 2, xc = (tid & 3) * 32;
    const size_t base = (size_t)(r0 + xr) * DN + xc;
#pragma unroll
    for (int j = 0; j < 4; j++) {
      float4 u = make_float4(0.f, 0.f, 0.f, 0.f);
      float4 v = make_float4(0.f, 0.f, 0.f, 0.f);
#pragma unroll
      for (int s = 0; s < SPLITS; s++) {
        const float4* p = (const float4*)(part + (size_t)s * NA * DN + base);
        u = f4add(u, p[2 * j]);
        v = f4add(v, p[2 * j + 1]);
      }
      uint4 w;
      w.x = pk2(u.x * scale, u.y * scale); w.y = pk2(u.z * scale, u.w * scale);
      w.z = pk2(v.x * scale, v.y * scale); w.w = pk2(v.z * scale, v.w * scale);
      st16(Xa, xr, (xc + j * 8) * 2, 256, w);
    }
  }

  const float* Wp[3] = {W1, W2, W3};
  const float* bp[3] = {b1, b2, b3};
  unsigned char* Xin = Xa;
  unsigned char* Xout = Xb;
  const int wrow = tid >> 1, wc = (tid & 1) * 64;

  for (int s = 0; s < 3; s++) {
    float4 wv[16];
    const float4* wg = (const float4*)(Wp[s] + (size_t)wrow * DN + wc);
#pragma unroll
    for (int j = 0; j < 16; j++) wv[j] = wg[j];
    float bb[8];
#pragma unroll
    for (int ct = 0; ct < 8; ct++) bb[ct] = bp[s][ct * 16 + lrow];

    __syncthreads();
#pragma unroll
    for (int j = 0; j < 8; j++) {
      uint4 w;
      w.x = pk2(wv[2 * j].x, wv[2 * j].y);         w.y = pk2(wv[2 * j].z, wv[2 * j].w);
      w.z = pk2(wv[2 * j + 1].x, wv[2 * j + 1].y); w.w = pk2(wv[2 * j + 1].z, wv[2 * j + 1].w);
      st16(Ws, wrow, (wc + j * 8) * 2, 256, w);
    }
    __syncthreads();

    f32x4 acc[8];
#pragma unroll
    for (int i = 0; i < 8; i++) acc[i] = (f32x4){0.f, 0.f, 0.f, 0.f};
#pragma unroll
    for (int kk = 0; kk < 128; kk += 32) {
      bf16x8 af = ld16(Xin, wr + lrow, (kk + kgrp) * 2, 256);
#pragma unroll
      for (int ct = 0; ct < 8; ct++) {
        bf16x8 bf = ld16(Ws, ct * 16 + lrow, (kk + kgrp) * 2, 256);
        acc[ct] = __builtin_amdgcn_mfma_f32_16x16x32_bf16(af, bf, acc[ct], 0, 0, 0);
      }
    }

    if (s < 2) {
#pragma unroll
      for (int ct = 0; ct < 8; ct++)
#pragma unroll
        for (int i = 0; i < 4; i++) {
          int row = wr + (lane >> 4) * 4 + i;
          int col = ct * 16 + lrow;
          float v = acc[ct][i] + bb[ct];
          v = v > 0.f ? v : 0.01f * v;
          st2(Xout, row, col * 2, 256, f2bf(v));
        }
      unsigned char* t = Xin; Xin = Xout; Xout = t;
    } else {
#pragma unroll
      for (int ct = 0; ct < 8; ct++)
#pragma unroll
        for (int i = 0; i < 4; i++) {
          int row = wr + (lane >> 4) * 4 + i;
          int col = ct * 16 + lrow;
          float v = acc[ct][i] + bb[ct];
          size_t gi = (size_t)(r0 + row) * DN + col;
          all_emb[gi] = v;
          embs_sum[gi] += v;
        }
    }
  }
}

// fused: pre = (users@items^T)*mask; partial[blk] = sum(w*|pre - tq|)
__global__ __launch_bounds__(256) void k_loss(const unsigned short* __restrict__ sbf,
                                              const float* __restrict__ tq,
                                              const float* __restrict__ lw,
                                              const int* __restrict__ msk,
                                              float* __restrict__ partial) {
  const unsigned short* ubf = sbf;
  const unsigned short* ibf = sbf + (size_t)UN * DN;
  const int r0 = blockIdx.x * 32;
  const int c0 = blockIdx.y * 128;
  const int tid = threadIdx.x;
  const int wave = tid >> 6, lane = tid & 63;
  const int wr = (wave >> 1) * 16;
  const int wc = (wave & 1) * 64;
  const int lrow = lane & 15;
  const int kgrp = (lane >> 4) * 8;

  f32x4 acc[4];
#pragma unroll
  for (int i = 0; i < 4; i++) acc[i] = (f32x4){0.f, 0.f, 0.f, 0.f};
#pragma unroll
  for (int kk = 0; kk < 128; kk += 32) {
    bf16x8 af = *(const bf16x8*)(ubf + (size_t)(r0 + wr + lrow) * DN + kk + kgrp);
#pragma unroll
    for (int ct = 0; ct < 4; ct++) {
      bf16x8 bf = *(const bf16x8*)(ibf + (size_t)(c0 + wc + ct * 16 + lrow) * DN + kk + kgrp);
      acc[ct] = __builtin_amdgcn_mfma_f32_16x16x32_bf16(af, bf, acc[ct], 0, 0, 0);
    }
  }
  float lsum = 0.f;
#pragma unroll
  for (int ct = 0; ct < 4; ct++)
#pragma unroll
    for (int i = 0; i < 4; i++) {
      int r = r0 + wr + (lane >> 4) * 4 + i;
      int c = c0 + wc + ct * 16 + lrow;
      size_t gi = (size_t)r * SN + c;
      float pre = msk[gi] ? acc[ct][i] : 0.f;
      lsum += lw[gi] * fabsf(pre - tq[gi]);
    }
  __shared__ float red[256];
  red[tid] = lsum;
  __syncthreads();
  for (int st = 128; st > 0; st >>= 1) {
    if (tid < st) red[tid] += red[tid + st];
    __syncthreads();
  }
  if (tid == 0) partial[blockIdx.x * 64 + blockIdx.y] = red[0];
}

__global__ void k_reduce(const float* __restrict__ p, float* __restrict__ out) {
  __shared__ float red[256];
  float s = 0.f;
  for (int i = threadIdx.x; i < 4096; i += 256) s += p[i];
  red[threadIdx.x] = s;
  __syncthreads();
  for (int st = 128; st > 0; st >>= 1) {
    if (threadIdx.x < st) red[threadIdx.x] += red[threadIdx.x + st];
    __syncthreads();
  }
  if (threadIdx.x == 0) out[0] = red[0];
}

extern "C" void kernel_launch(void* const* d_in, const int* in_sizes, int n_in,
                              void* d_out, int out_size, void* d_ws, size_t ws_size,
                              hipStream_t stream) {
  const float* user_emb = (const float*)d_in[0];
  const float* item_emb = (const float*)d_in[1];
  const float* grpha    = (const float*)d_in[2];
  const float* W1 = (const float*)d_in[3];
  const float* b1 = (const float*)d_in[4];
  const float* W2 = (const float*)d_in[5];
  const float* b2 = (const float*)d_in[6];
  const float* W3 = (const float*)d_in[7];
  const float* b3 = (const float*)d_in[8];
  const float* tq = (const float*)d_in[9];
  const float* lw = (const float*)d_in[10];
  const int* msk  = (const int*)d_in[11];
  float* out = (float*)d_out;

  char* ws = (char*)d_ws;
  unsigned short* A_bf = (unsigned short*)ws;    ws += (size_t)NA * NA * 2;        // 210 MB
  float* all_emb  = (float*)ws;                  ws += (size_t)NA * DN * 4;
  float* embs_sum = (float*)ws;                  ws += (size_t)NA * DN * 4;
  float* part     = (float*)ws;                  ws += (size_t)SPLITS * NA * DN * 4;
  unsigned short* Bt  = (unsigned short*)ws;     ws += (size_t)NA * DN * 2;
  unsigned short* sbf = (unsigned short*)ws;     ws += (size_t)NA * DN * 2;
  float* lpart    = (float*)ws;                  ws += 4096 * 4;

  // grpha fp32 -> bf16, once (NA*NA/8 elems-of-8 / 256 threads)
  k_cvt<<<(NA * NA / 8) / 256, 256, 0, stream>>>(grpha, A_bf);
  k_init<<<1280, 256, 0, stream>>>((const float4*)user_emb, (const float4*)item_emb,
                                   (float4*)all_emb, (float4*)embs_sum);
  for (int layer = 0; layer < 3; layer++) {
    k_bt<<<dim3(320, 4), 256, 0, stream>>>(all_emb, Bt);
    k_gemm<<<dim3(SPLITS, NA / 128), 256, 0, stream>>>(A_bf, Bt, part);
    k_transform<<<160, 256, 0, stream>>>(part, 1.0f / (1.0f + (float)layer),
                                         W1, b1, W2, b2, W3, b3, all_emb, embs_sum);
  }
  k_cvt<<<(NA * DN / 8) / 256, 256, 0, stream>>>(embs_sum, sbf);
  k_loss<<<dim3(64, 64), 256, 0, stream>>>(sbf, tq, lw, msk, lpart);
  k_reduce<<<1, 256, 0, stream>>>(lpart, out);
}

// Round 3
// 460.622 us; speedup vs baseline: 1.2415x; 1.1107x over previous
//
#include <hip/hip_runtime.h>
#include <hip/hip_bf16.h>

#define UN 2048
#define SN 8192
#define NA 10240
#define DN 128
#define SPLITS 8
#define KSPL (NA / SPLITS)  // 1280
#define BK 64
#define KT (KSPL / BK)      // 20

typedef __attribute__((ext_vector_type(8))) short bf16x8;
typedef __attribute__((ext_vector_type(4))) float f32x4;

__device__ __forceinline__ unsigned short f2bf(float f) {
  unsigned int u = __builtin_bit_cast(unsigned int, f);
  u += 0x7fffu + ((u >> 16) & 1u);
  return (unsigned short)(u >> 16);
}
__device__ __forceinline__ unsigned int pk2(float a, float b) {
  return (unsigned int)f2bf(a) | ((unsigned int)f2bf(b) << 16);
}
__device__ __forceinline__ float4 f4add(float4 a, float4 b) {
  return make_float4(a.x + b.x, a.y + b.y, a.z + b.z, a.w + b.w);
}
// async global->LDS, 16B per lane (dest = wave-uniform base + lane*16)
__device__ __forceinline__ void gl_lds16(const void* g, void* l) {
  __builtin_amdgcn_global_load_lds((const __attribute__((address_space(1))) unsigned int*)g,
                                   (__attribute__((address_space(3))) unsigned int*)l, 16, 0, 0);
}
// swizzled LDS helpers (chunk-XOR within 128B row stripes)
__device__ __forceinline__ void st16(unsigned char* base, int row, int cb, int stride, uint4 v) {
  int off = row * stride + cb;
  off ^= (row & 7) << 4;
  *(uint4*)(base + off) = v;
}
__device__ __forceinline__ bf16x8 ld16(const unsigned char* base, int row, int cb, int stride) {
  int off = row * stride + cb;
  off ^= (row & 7) << 4;
  return *(const bf16x8*)(base + off);
}
__device__ __forceinline__ void st2(unsigned char* base, int row, int cb, int stride, unsigned short h) {
  int off = row * stride + cb;
  off ^= (row & 7) << 4;
  *(unsigned short*)(base + off) = h;
}

// all_emb = concat(user_emb, item_emb); embs_sum = all_emb
__global__ void k_init(const float4* __restrict__ ue, const float4* __restrict__ ie,
                       float4* __restrict__ ae, float4* __restrict__ es) {
  int i = blockIdx.x * 256 + threadIdx.x;
  float4 v = (i < UN * DN / 4) ? ue[i] : ie[i - UN * DN / 4];
  ae[i] = v;
  es[i] = v;
}

// Bt[c][r] = bf16(x[r][c]); tiled transpose via LDS
__global__ void k_bt(const float* __restrict__ x, unsigned short* __restrict__ bt) {
  __shared__ float tile[32][33];
  const int tr = blockIdx.x;  // 0..319
  const int tc = blockIdx.y;  // 0..3
  const int lr = threadIdx.x / 32, lc = threadIdx.x % 32;
#pragma unroll
  for (int i = 0; i < 4; i++)
    tile[lr + i * 8][lc] = x[(size_t)(tr * 32 + lr + i * 8) * DN + tc * 32 + lc];
  __syncthreads();
#pragma unroll
  for (int i = 0; i < 4; i++)
    bt[(size_t)(tc * 32 + lr + i * 8) * NA + tr * 32 + lc] = f2bf(tile[lc][lr + i * 8]);
}

// fp32 -> bf16 stream (8 elems/thread)
__global__ void k_cvt(const float* __restrict__ x, unsigned short* __restrict__ y) {
  size_t i = (size_t)blockIdx.x * 256 + threadIdx.x;
  const float4* p = (const float4*)(x + i * 8);
  float4 a = p[0], b = p[1];
  uint4 w;
  w.x = pk2(a.x, a.y); w.y = pk2(a.z, a.w);
  w.z = pk2(b.x, b.y); w.w = pk2(b.z, b.w);
  ((uint4*)y)[i] = w;
}

// W1,W2,W3 -> bf16, PRE-SWIZZLED so gl_lds16 (linear) + ld16 (XOR) agree.
// wbf[mat] element offset: r*128 + (cg ^ (r&7))*8 holds W[r][cg*8..cg*8+8)
__global__ void k_wcvt(const float* __restrict__ W1, const float* __restrict__ W2,
                       const float* __restrict__ W3, unsigned short* __restrict__ wbf) {
  int g = blockIdx.x * 256 + threadIdx.x;  // 24*256 = 6144 groups of 8
  int mat = g / 2048;
  int idx = g % 2048;
  int r = idx / 16, cg = idx % 16;
  const float* Wp = (mat == 0) ? W1 : (mat == 1) ? W2 : W3;
  const float4* src = (const float4*)(Wp + (size_t)r * DN + cg * 8);
  float4 a = src[0], b = src[1];
  uint4 w;
  w.x = pk2(a.x, a.y); w.y = pk2(a.z, a.w);
  w.z = pk2(b.x, b.y); w.w = pk2(b.z, b.w);
  *(uint4*)(wbf + (size_t)mat * 16384 + r * 128 + ((cg ^ (r & 7)) * 8)) = w;
}

// part[ks] = A_bf16[:, ks-chunk] @ Bt[ks-chunk]^T
// BM=128, BN=128, BK=64, global_load_lds w16, DOUBLE-BUFFERED prefetch (T3 2-phase).
__global__ __launch_bounds__(256, 4) void k_gemm(const unsigned short* __restrict__ A,
                                                 const unsigned short* __restrict__ Bt,
                                                 float* __restrict__ part) {
  __shared__ unsigned short As[2][128 * 64];  // 2 x 16 KB
  __shared__ unsigned short Bs[2][128 * 64];  // 2 x 16 KB
  const int ks = blockIdx.x;
  const int m0 = blockIdx.y * 128;
  const int k0 = ks * KSPL;
  const int tid = threadIdx.x;
  const int wave = tid >> 6, lane = tid & 63;
  const int lrow = lane & 15;
  const int kq = lane >> 4;
  const int wr = (wave >> 1) * 64;
  const int wc = (wave & 1) * 64;

  auto stage = [&](int buf, int kt) {
    const int kg = k0 + kt * BK;
#pragma unroll
    for (int j = 0; j < 4; j++) {
      const int L = j * 256 + tid;
      const int row = L >> 3, c = L & 7;
      const int sc = (c ^ (row & 7)) << 3;  // inverse-swizzled global source
      gl_lds16(A + (size_t)(m0 + row) * NA + kg + sc, (char*)As[buf] + L * 16);
      gl_lds16(Bt + (size_t)row * NA + kg + sc, (char*)Bs[buf] + L * 16);
    }
  };

  f32x4 acc[4][4];
#pragma unroll
  for (int fi = 0; fi < 4; fi++)
#pragma unroll
    for (int fj = 0; fj < 4; fj++) acc[fi][fj] = (f32x4){0.f, 0.f, 0.f, 0.f};

  stage(0, 0);
  int cur = 0;
  for (int kt = 0; kt < KT; kt++) {
    __syncthreads();  // drains vmcnt: buf[cur] ready; all waves' prior LDS reads done
    if (kt + 1 < KT) stage(cur ^ 1, kt + 1);  // prefetch overlaps compute below
#pragma unroll
    for (int ks2 = 0; ks2 < 2; ks2++) {
      const int kc = ks2 * 4 + kq;
      bf16x8 av[4], bv[4];
#pragma unroll
      for (int fi = 0; fi < 4; fi++) {
        const int row = wr + fi * 16 + lrow;
        av[fi] = *(const bf16x8*)((const char*)As[cur] + row * 128 + ((kc ^ (row & 7)) << 4));
      }
#pragma unroll
      for (int fj = 0; fj < 4; fj++) {
        const int row = wc + fj * 16 + lrow;
        bv[fj] = *(const bf16x8*)((const char*)Bs[cur] + row * 128 + ((kc ^ (row & 7)) << 4));
      }
#pragma unroll
      for (int fi = 0; fi < 4; fi++)
#pragma unroll
        for (int fj = 0; fj < 4; fj++)
          acc[fi][fj] = __builtin_amdgcn_mfma_f32_16x16x32_bf16(av[fi], bv[fj], acc[fi][fj], 0, 0, 0);
    }
    cur ^= 1;
  }

  float* op = part + (size_t)ks * NA * DN;
#pragma unroll
  for (int fi = 0; fi < 4; fi++) {
    const int row0 = m0 + wr + fi * 16 + kq * 4;
#pragma unroll
    for (int fj = 0; fj < 4; fj++) {
      const int col = wc + fj * 16 + lrow;
#pragma unroll
      for (int i = 0; i < 4; i++)
        op[(size_t)(row0 + i) * DN + col] = acc[fi][fj][i];
    }
  }
}

// x = (sum of SPLITS partials)*scale; 3-layer MLP; all_emb = x; embs_sum += x
// 32 rows/block (320 blocks); W staged bf16 via gl_lds16, double-buffered.
__global__ __launch_bounds__(256) void k_transform(
    const float* __restrict__ part, float scale,
    const unsigned short* __restrict__ wbf,
    const float* __restrict__ b1, const float* __restrict__ b2, const float* __restrict__ b3,
    float* __restrict__ all_emb, float* __restrict__ embs_sum) {
  __shared__ unsigned char Ws[2][128 * 128 * 2];  // 2 x 32 KB
  __shared__ unsigned char Xa[32 * 128 * 2];      // 8 KB
  __shared__ unsigned char Xb[32 * 128 * 2];      // 8 KB
  const int r0 = blockIdx.x * 32;
  const int tid = threadIdx.x;
  const int wave = tid >> 6, lane = tid & 63;
  const int lrow = lane & 15;
  const int kq = lane >> 4;
  const int kgrp = kq * 8;
  const int rh = (wave & 1) * 16;   // row half
  const int ch = (wave >> 1) * 64;  // col half

  auto stage_W = [&](int buf, int s) {
#pragma unroll
    for (int j = 0; j < 8; j++) {
      const int L = j * 256 + tid;  // 2048 chunks of 16B = 32 KB
      gl_lds16(wbf + (size_t)s * 16384 + L * 8, (char*)Ws[buf] + L * 16);
    }
  };

  stage_W(0, 0);
  {  // stage input tile into Xa (bf16, swizzled): 32 rows x 128 cols
    const int xr = tid >> 3, xc = (tid & 7) * 16;
    const size_t base = (size_t)(r0 + xr) * DN + xc;
    float4 u[4];
#pragma unroll
    for (int q = 0; q < 4; q++) u[q] = make_float4(0.f, 0.f, 0.f, 0.f);
#pragma unroll
    for (int s = 0; s < SPLITS; s++) {
      const float4* p = (const float4*)(part + (size_t)s * NA * DN + base);
#pragma unroll
      for (int q = 0; q < 4; q++) u[q] = f4add(u[q], p[q]);
    }
#pragma unroll
    for (int h = 0; h < 2; h++) {
      uint4 w;
      w.x = pk2(u[2 * h].x * scale, u[2 * h].y * scale);
      w.y = pk2(u[2 * h].z * scale, u[2 * h].w * scale);
      w.z = pk2(u[2 * h + 1].x * scale, u[2 * h + 1].y * scale);
      w.w = pk2(u[2 * h + 1].z * scale, u[2 * h + 1].w * scale);
      st16(Xa, xr, (xc + h * 8) * 2, 256, w);
    }
  }

  const float* bp[3] = {b1, b2, b3};
  unsigned char* Xin = Xa;
  unsigned char* Xout = Xb;
  int cw = 0;

  for (int s = 0; s < 3; s++) {
    __syncthreads();  // W[cw] staged; prior stage's LDS reads/writes settled
    if (s < 2) stage_W(cw ^ 1, s + 1);
    float bb[4];
#pragma unroll
    for (int ct = 0; ct < 4; ct++) bb[ct] = bp[s][ch + ct * 16 + lrow];

    f32x4 acc[4];
#pragma unroll
    for (int i = 0; i < 4; i++) acc[i] = (f32x4){0.f, 0.f, 0.f, 0.f};
#pragma unroll
    for (int kk = 0; kk < 128; kk += 32) {
      bf16x8 af = ld16(Xin, rh + lrow, (kk + kgrp) * 2, 256);
#pragma unroll
      for (int ct = 0; ct < 4; ct++) {
        bf16x8 bf = ld16(Ws[cw], ch + ct * 16 + lrow, (kk + kgrp) * 2, 256);
        acc[ct] = __builtin_amdgcn_mfma_f32_16x16x32_bf16(af, bf, acc[ct], 0, 0, 0);
      }
    }

    if (s < 2) {
#pragma unroll
      for (int ct = 0; ct < 4; ct++)
#pragma unroll
        for (int i = 0; i < 4; i++) {
          int row = rh + kq * 4 + i;
          int col = ch + ct * 16 + lrow;
          float v = acc[ct][i] + bb[ct];
          v = v > 0.f ? v : 0.01f * v;
          st2(Xout, row, col * 2, 256, f2bf(v));
        }
      unsigned char* t = Xin; Xin = Xout; Xout = t;
    } else {
#pragma unroll
      for (int ct = 0; ct < 4; ct++)
#pragma unroll
        for (int i = 0; i < 4; i++) {
          int row = rh + kq * 4 + i;
          int col = ch + ct * 16 + lrow;
          float v = acc[ct][i] + bb[ct];
          size_t gi = (size_t)(r0 + row) * DN + col;
          all_emb[gi] = v;
          embs_sum[gi] += v;
        }
    }
    cw ^= 1;
  }
}

// fused: pre = (users@items^T)*mask; partial[blk] = sum(w*|pre - tq|)
__global__ __launch_bounds__(256) void k_loss(const unsigned short* __restrict__ sbf,
                                              const float* __restrict__ tq,
                                              const float* __restrict__ lw,
                                              const int* __restrict__ msk,
                                              float* __restrict__ partial) {
  const unsigned short* ubf = sbf;
  const unsigned short* ibf = sbf + (size_t)UN * DN;
  const int r0 = blockIdx.x * 32;
  const int c0 = blockIdx.y * 128;
  const int tid = threadIdx.x;
  const int wave = tid >> 6, lane = tid & 63;
  const int wr = (wave >> 1) * 16;
  const int wc = (wave & 1) * 64;
  const int lrow = lane & 15;
  const int kgrp = (lane >> 4) * 8;

  f32x4 acc[4];
#pragma unroll
  for (int i = 0; i < 4; i++) acc[i] = (f32x4){0.f, 0.f, 0.f, 0.f};
#pragma unroll
  for (int kk = 0; kk < 128; kk += 32) {
    bf16x8 af = *(const bf16x8*)(ubf + (size_t)(r0 + wr + lrow) * DN + kk + kgrp);
#pragma unroll
    for (int ct = 0; ct < 4; ct++) {
      bf16x8 bf = *(const bf16x8*)(ibf + (size_t)(c0 + wc + ct * 16 + lrow) * DN + kk + kgrp);
      acc[ct] = __builtin_amdgcn_mfma_f32_16x16x32_bf16(af, bf, acc[ct], 0, 0, 0);
    }
  }
  float lsum = 0.f;
#pragma unroll
  for (int ct = 0; ct < 4; ct++)
#pragma unroll
    for (int i = 0; i < 4; i++) {
      int r = r0 + wr + (lane >> 4) * 4 + i;
      int c = c0 + wc + ct * 16 + lrow;
      size_t gi = (size_t)r * SN + c;
      float pre = msk[gi] ? acc[ct][i] : 0.f;
      lsum += lw[gi] * fabsf(pre - tq[gi]);
    }
  __shared__ float red[256];
  red[tid] = lsum;
  __syncthreads();
  for (int st = 128; st > 0; st >>= 1) {
    if (tid < st) red[tid] += red[tid + st];
    __syncthreads();
  }
  if (tid == 0) partial[blockIdx.x * 64 + blockIdx.y] = red[0];
}

__global__ void k_reduce(const float* __restrict__ p, float* __restrict__ out) {
  __shared__ float red[256];
  float s = 0.f;
  for (int i = threadIdx.x; i < 4096; i += 256) s += p[i];
  red[threadIdx.x] = s;
  __syncthreads();
  for (int st = 128; st > 0; st >>= 1) {
    if (threadIdx.x < st) red[threadIdx.x] += red[threadIdx.x + st];
    __syncthreads();
  }
  if (threadIdx.x == 0) out[0] = red[0];
}

extern "C" void kernel_launch(void* const* d_in, const int* in_sizes, int n_in,
                              void* d_out, int out_size, void* d_ws, size_t ws_size,
                              hipStream_t stream) {
  const float* user_emb = (const float*)d_in[0];
  const float* item_emb = (const float*)d_in[1];
  const float* grpha    = (const float*)d_in[2];
  const float* W1 = (const float*)d_in[3];
  const float* b1 = (const float*)d_in[4];
  const float* W2 = (const float*)d_in[5];
  const float* b2 = (const float*)d_in[6];
  const float* W3 = (const float*)d_in[7];
  const float* b3 = (const float*)d_in[8];
  const float* tq = (const float*)d_in[9];
  const float* lw = (const float*)d_in[10];
  const int* msk  = (const int*)d_in[11];
  float* out = (float*)d_out;

  char* ws = (char*)d_ws;
  unsigned short* A_bf = (unsigned short*)ws;    ws += (size_t)NA * NA * 2;
  float* all_emb  = (float*)ws;                  ws += (size_t)NA * DN * 4;
  float* embs_sum = (float*)ws;                  ws += (size_t)NA * DN * 4;
  float* part     = (float*)ws;                  ws += (size_t)SPLITS * NA * DN * 4;
  unsigned short* Bt  = (unsigned short*)ws;     ws += (size_t)NA * DN * 2;
  unsigned short* sbf = (unsigned short*)ws;     ws += (size_t)NA * DN * 2;
  unsigned short* wbf = (unsigned short*)ws;     ws += (size_t)3 * DN * DN * 2;
  float* lpart    = (float*)ws;                  ws += 4096 * 4;

  k_cvt<<<(NA * NA / 8) / 256, 256, 0, stream>>>(grpha, A_bf);
  k_init<<<1280, 256, 0, stream>>>((const float4*)user_emb, (const float4*)item_emb,
                                   (float4*)all_emb, (float4*)embs_sum);
  k_wcvt<<<24, 256, 0, stream>>>(W1, W2, W3, wbf);
  for (int layer = 0; layer < 3; layer++) {
    k_bt<<<dim3(320, 4), 256, 0, stream>>>(all_emb, Bt);
    k_gemm<<<dim3(SPLITS, NA / 128), 256, 0, stream>>>(A_bf, Bt, part);
    k_transform<<<320, 256, 0, stream>>>(part, 1.0f / (1.0f + (float)layer),
                                         wbf, b1, b2, b3, all_emb, embs_sum);
  }
  k_cvt<<<(NA * DN / 8) / 256, 256, 0, stream>>>(embs_sum, sbf);
  k_loss<<<dim3(64, 64), 256, 0, stream>>>(sbf, tq, lw, msk, lpart);
  k_reduce<<<1, 256, 0, stream>>>(lpart, out);
}

// Round 4
// 366.623 us; speedup vs baseline: 1.5598x; 1.2564x over previous
//
#include <hip/hip_runtime.h>
#include <hip/hip_bf16.h>

#define UN 2048
#define SN 8192
#define NA 10240
#define DN 128
#define SPLITS 8
#define KSPL (NA / SPLITS)  // 1280
#define BK 64
#define KT (KSPL / BK)      // 20

typedef __attribute__((ext_vector_type(8))) short bf16x8;
typedef __attribute__((ext_vector_type(4))) float f32x4;

__device__ __forceinline__ unsigned short f2bf(float f) {
  unsigned int u = __builtin_bit_cast(unsigned int, f);
  u += 0x7fffu + ((u >> 16) & 1u);
  return (unsigned short)(u >> 16);
}
__device__ __forceinline__ unsigned int pk2(float a, float b) {
  return (unsigned int)f2bf(a) | ((unsigned int)f2bf(b) << 16);
}

// ---- fp8 e4m3fn packing (scaled upstream) ----
#if __has_builtin(__builtin_amdgcn_cvt_pk_fp8_f32)
__device__ __forceinline__ unsigned int pkfp8_4(float a, float b, float c, float d) {
  int w = __builtin_amdgcn_cvt_pk_fp8_f32(a, b, 0, false);
  w = __builtin_amdgcn_cvt_pk_fp8_f32(c, d, w, true);
  return (unsigned int)w;
}
#else
__device__ __forceinline__ unsigned char f2e4m3(float f) {
  unsigned int u = __builtin_bit_cast(unsigned int, f);
  unsigned int s = (u >> 24) & 0x80u;
  unsigned int a = u & 0x7fffffffu;
  if (a < 0x3c800000u) return (unsigned char)s;   // |x| < 2^-6 -> 0
  if (a > 0x43e00000u) a = 0x43e00000u;           // clamp to 448
  a += 0x7ffffu + ((a >> 20) & 1u);               // RNE at bit 20
  unsigned int e = (a >> 23) - 120u;
  unsigned int m = (a >> 20) & 7u;
  if (e > 15u) { e = 15u; m = 6u; }
  return (unsigned char)(s | (e << 3) | m);
}
__device__ __forceinline__ unsigned int pkfp8_4(float a, float b, float c, float d) {
  return (unsigned int)f2e4m3(a) | ((unsigned int)f2e4m3(b) << 8) |
         ((unsigned int)f2e4m3(c) << 16) | ((unsigned int)f2e4m3(d) << 24);
}
#endif

// async global->LDS, 16B per lane (dest = wave-uniform base + lane*16)
__device__ __forceinline__ void gl_lds16(const void* g, void* l) {
  __builtin_amdgcn_global_load_lds((const __attribute__((address_space(1))) unsigned int*)g,
                                   (__attribute__((address_space(3))) unsigned int*)l, 16, 0, 0);
}
// swizzled LDS helpers (bf16 tiles in k_transform)
__device__ __forceinline__ void st16(unsigned char* base, int row, int cb, int stride, uint4 v) {
  int off = row * stride + cb;
  off ^= (row & 7) << 4;
  *(uint4*)(base + off) = v;
}
__device__ __forceinline__ bf16x8 ld16(const unsigned char* base, int row, int cb, int stride) {
  int off = row * stride + cb;
  off ^= (row & 7) << 4;
  return *(const bf16x8*)(base + off);
}
__device__ __forceinline__ void st2(unsigned char* base, int row, int cb, int stride, unsigned short h) {
  int off = row * stride + cb;
  off ^= (row & 7) << 4;
  *(unsigned short*)(base + off) = h;
}

// all_emb = concat(user_emb, item_emb); embs_sum = all_emb
__global__ void k_init(const float4* __restrict__ ue, const float4* __restrict__ ie,
                       float4* __restrict__ ae, float4* __restrict__ es) {
  int i = blockIdx.x * 256 + threadIdx.x;
  float4 v = (i < UN * DN / 4) ? ue[i] : ie[i - UN * DN / 4];
  ae[i] = v;
  es[i] = v;
}

// grpha fp32 -> fp8 (x4096), permuted image:
// byte at r*NA + s*64 + q*16, q = gg^(r&3); content j<8: x[r][s*64+gg*8+j], j>=8: +32.
__global__ void k_cvt8(const float* __restrict__ x, unsigned char* __restrict__ y) {
  size_t gid = (size_t)blockIdx.x * 256 + threadIdx.x;  // NA*NA/16 = 6.55M granules
  int r = (int)(gid / 640);
  int w = (int)(gid % 640);
  int s = w >> 2, gg = w & 3;
  const float* p1 = x + (size_t)r * NA + s * 64 + gg * 8;
  float4 a0 = *(const float4*)p1, a1 = *(const float4*)(p1 + 4);
  float4 b0 = *(const float4*)(p1 + 32), b1 = *(const float4*)(p1 + 36);
  const float S = 4096.f;
  uint4 o;
  o.x = pkfp8_4(a0.x * S, a0.y * S, a0.z * S, a0.w * S);
  o.y = pkfp8_4(a1.x * S, a1.y * S, a1.z * S, a1.w * S);
  o.z = pkfp8_4(b0.x * S, b0.y * S, b0.z * S, b0.w * S);
  o.w = pkfp8_4(b1.x * S, b1.y * S, b1.z * S, b1.w * S);
  *(uint4*)(y + (size_t)r * NA + s * 64 + ((gg ^ (r & 3)) * 16)) = o;
}

// all_emb fp32 -> Bt fp8 (x1024), transposed, same permuted image keyed by row c.
__global__ void k_bt8(const float* __restrict__ emb, unsigned char* __restrict__ bt) {
  int gid = blockIdx.x * 256 + threadIdx.x;  // DN * 640 = 81920
  int c = gid & 127;
  int w = gid >> 7;
  int s = w >> 2, gg = w & 3;
  float v[16];
#pragma unroll
  for (int j = 0; j < 8; j++) v[j] = emb[(size_t)(s * 64 + gg * 8 + j) * DN + c];
#pragma unroll
  for (int j = 0; j < 8; j++) v[8 + j] = emb[(size_t)(s * 64 + 32 + gg * 8 + j) * DN + c];
  const float S = 1024.f;
  uint4 o;
  o.x = pkfp8_4(v[0] * S, v[1] * S, v[2] * S, v[3] * S);
  o.y = pkfp8_4(v[4] * S, v[5] * S, v[6] * S, v[7] * S);
  o.z = pkfp8_4(v[8] * S, v[9] * S, v[10] * S, v[11] * S);
  o.w = pkfp8_4(v[12] * S, v[13] * S, v[14] * S, v[15] * S);
  *(uint4*)(bt + (size_t)c * NA + s * 64 + ((gg ^ (c & 3)) * 16)) = o;
}

// embs_sum fp32 -> bf16 stream (8 elems/thread)
__global__ void k_cvt(const float* __restrict__ x, unsigned short* __restrict__ y) {
  size_t i = (size_t)blockIdx.x * 256 + threadIdx.x;
  const float4* p = (const float4*)(x + i * 8);
  float4 a = p[0], b = p[1];
  uint4 w;
  w.x = pk2(a.x, a.y); w.y = pk2(a.z, a.w);
  w.z = pk2(b.x, b.y); w.w = pk2(b.z, b.w);
  ((uint4*)y)[i] = w;
}

// W1,W2,W3 -> bf16, pre-swizzled for gl_lds16 + ld16
__global__ void k_wcvt(const float* __restrict__ W1, const float* __restrict__ W2,
                       const float* __restrict__ W3, unsigned short* __restrict__ wbf) {
  int g = blockIdx.x * 256 + threadIdx.x;
  int mat = g / 2048;
  int idx = g % 2048;
  int r = idx / 16, cg = idx % 16;
  const float* Wp = (mat == 0) ? W1 : (mat == 1) ? W2 : W3;
  const float4* src = (const float4*)(Wp + (size_t)r * DN + cg * 8);
  float4 a = src[0], b = src[1];
  uint4 w;
  w.x = pk2(a.x, a.y); w.y = pk2(a.z, a.w);
  w.z = pk2(b.x, b.y); w.w = pk2(b.z, b.w);
  *(uint4*)(wbf + (size_t)mat * 16384 + r * 128 + ((cg ^ (r & 7)) * 8)) = w;
}

// part[ks] = A8[:, ks-chunk] @ Bt8[ks-chunk]^T  (fp8 MFMA, bf16 part out)
__global__ __launch_bounds__(256, 4) void k_gemm(const unsigned char* __restrict__ A8,
                                                 const unsigned char* __restrict__ B8,
                                                 unsigned short* __restrict__ part) {
  __shared__ __align__(16) unsigned char As[2][128 * 64];  // 2 x 8 KB
  __shared__ __align__(16) unsigned char Bs[2][128 * 64];  // 2 x 8 KB
  const int ks = blockIdx.x;
  const int m0 = blockIdx.y * 128;
  const size_t k0b = (size_t)ks * KSPL;  // byte offset (1 B/elem)
  const int tid = threadIdx.x;
  const int wave = tid >> 6, lane = tid & 63;
  const int lrow = lane & 15;
  const int kq = lane >> 4;
  const int wr = (wave >> 1) * 64;
  const int wc = (wave & 1) * 64;
  const int swz = (kq ^ (lrow & 3)) << 4;  // lane-constant granule swizzle

  auto stage = [&](int buf, int kt) {
    const size_t kgb = k0b + (size_t)kt * BK;
#pragma unroll
    for (int j = 0; j < 2; j++) {
      const int L = j * 256 + tid;  // 0..511 granules
      const int row = L >> 2, q = L & 3;
      gl_lds16(A8 + (size_t)(m0 + row) * NA + kgb + q * 16, (char*)As[buf] + L * 16);
      gl_lds16(B8 + (size_t)row * NA + kgb + q * 16, (char*)Bs[buf] + L * 16);
    }
  };

  f32x4 acc[4][4];  // [fj][fi]
#pragma unroll
  for (int fj = 0; fj < 4; fj++)
#pragma unroll
    for (int fi = 0; fi < 4; fi++) acc[fj][fi] = (f32x4){0.f, 0.f, 0.f, 0.f};

  stage(0, 0);
  int cur = 0;
  for (int kt = 0; kt < KT; kt++) {
    __syncthreads();  // buf[cur] staged; prior reads done
    if (kt + 1 < KT) stage(cur ^ 1, kt + 1);  // prefetch overlaps compute
    long2 av[4], bv[4];
#pragma unroll
    for (int fi = 0; fi < 4; fi++)
      av[fi] = *(const long2*)((const char*)As[cur] + (wr + fi * 16 + lrow) * 64 + swz);
#pragma unroll
    for (int fj = 0; fj < 4; fj++)
      bv[fj] = *(const long2*)((const char*)Bs[cur] + (wc + fj * 16 + lrow) * 64 + swz);
#pragma unroll
    for (int fj = 0; fj < 4; fj++)
#pragma unroll
      for (int fi = 0; fi < 4; fi++) {
        acc[fj][fi] = __builtin_amdgcn_mfma_f32_16x16x32_fp8_fp8(bv[fj].x, av[fi].x, acc[fj][fi], 0, 0, 0);
        acc[fj][fi] = __builtin_amdgcn_mfma_f32_16x16x32_fp8_fp8(bv[fj].y, av[fi].y, acc[fj][fi], 0, 0, 0);
      }
    cur ^= 1;
  }

  // operand-swapped D: row=n (kq*4+i), col=m (lrow) -> lane holds 4 consecutive n
  unsigned short* op = part + (size_t)ks * NA * DN;
#pragma unroll
  for (int fi = 0; fi < 4; fi++) {
    const size_t mrow = (size_t)(m0 + wr + fi * 16 + lrow) * DN;
#pragma unroll
    for (int fj = 0; fj < 4; fj++) {
      const int n = wc + fj * 16 + kq * 4;
      uint2 pkd;
      pkd.x = pk2(acc[fj][fi][0], acc[fj][fi][1]);
      pkd.y = pk2(acc[fj][fi][2], acc[fj][fi][3]);
      *(uint2*)(op + mrow + n) = pkd;
    }
  }
}

// x = (sum of SPLITS bf16 partials)*scale; 3-layer MLP; all_emb = x; embs_sum += x
__global__ __launch_bounds__(256) void k_transform(
    const unsigned short* __restrict__ part, float scale,
    const unsigned short* __restrict__ wbf,
    const float* __restrict__ b1, const float* __restrict__ b2, const float* __restrict__ b3,
    float* __restrict__ all_emb, float* __restrict__ embs_sum) {
  __shared__ __align__(16) unsigned char Ws[2][128 * 128 * 2];  // 2 x 32 KB
  __shared__ __align__(16) unsigned char Xa[32 * 128 * 2];      // 8 KB
  __shared__ __align__(16) unsigned char Xb[32 * 128 * 2];      // 8 KB
  const int r0 = blockIdx.x * 32;
  const int tid = threadIdx.x;
  const int wave = tid >> 6, lane = tid & 63;
  const int lrow = lane & 15;
  const int kq = lane >> 4;
  const int kgrp = kq * 8;
  const int rh = (wave & 1) * 16;
  const int ch = (wave >> 1) * 64;

  auto stage_W = [&](int buf, int s) {
#pragma unroll
    for (int j = 0; j < 8; j++) {
      const int L = j * 256 + tid;
      gl_lds16(wbf + (size_t)s * 16384 + L * 8, (char*)Ws[buf] + L * 16);
    }
  };

  stage_W(0, 0);
  {  // stage input tile into Xa: sum 8 bf16 slabs -> fp32 -> scale -> bf16
    const int xr = tid >> 3, xc = (tid & 7) * 16;
    const size_t base = (size_t)(r0 + xr) * DN + xc;
    float xs[16];
#pragma unroll
    for (int q = 0; q < 16; q++) xs[q] = 0.f;
#pragma unroll
    for (int s = 0; s < SPLITS; s++) {
      const unsigned short* p = part + (size_t)s * NA * DN + base;
      uint4 w1 = *(const uint4*)p;
      uint4 w2 = *(const uint4*)(p + 8);
      const unsigned int wsv[8] = {w1.x, w1.y, w1.z, w1.w, w2.x, w2.y, w2.z, w2.w};
#pragma unroll
      for (int q = 0; q < 8; q++) {
        xs[2 * q]     += __builtin_bit_cast(float, wsv[q] << 16);
        xs[2 * q + 1] += __builtin_bit_cast(float, wsv[q] & 0xffff0000u);
      }
    }
    uint4 w;
    w.x = pk2(xs[0] * scale, xs[1] * scale);  w.y = pk2(xs[2] * scale, xs[3] * scale);
    w.z = pk2(xs[4] * scale, xs[5] * scale);  w.w = pk2(xs[6] * scale, xs[7] * scale);
    st16(Xa, xr, xc * 2, 256, w);
    w.x = pk2(xs[8] * scale, xs[9] * scale);  w.y = pk2(xs[10] * scale, xs[11] * scale);
    w.z = pk2(xs[12] * scale, xs[13] * scale); w.w = pk2(xs[14] * scale, xs[15] * scale);
    st16(Xa, xr, (xc + 8) * 2, 256, w);
  }

  const float* bp[3] = {b1, b2, b3};
  unsigned char* Xin = Xa;
  unsigned char* Xout = Xb;
  int cw = 0;

  for (int s = 0; s < 3; s++) {
    __syncthreads();
    if (s < 2) stage_W(cw ^ 1, s + 1);
    float bb[4];
#pragma unroll
    for (int ct = 0; ct < 4; ct++) bb[ct] = bp[s][ch + ct * 16 + lrow];

    f32x4 acc[4];
#pragma unroll
    for (int i = 0; i < 4; i++) acc[i] = (f32x4){0.f, 0.f, 0.f, 0.f};
#pragma unroll
    for (int kk = 0; kk < 128; kk += 32) {
      bf16x8 af = ld16(Xin, rh + lrow, (kk + kgrp) * 2, 256);
#pragma unroll
      for (int ct = 0; ct < 4; ct++) {
        bf16x8 bf = ld16(Ws[cw], ch + ct * 16 + lrow, (kk + kgrp) * 2, 256);
        acc[ct] = __builtin_amdgcn_mfma_f32_16x16x32_bf16(af, bf, acc[ct], 0, 0, 0);
      }
    }

    if (s < 2) {
#pragma unroll
      for (int ct = 0; ct < 4; ct++)
#pragma unroll
        for (int i = 0; i < 4; i++) {
          int row = rh + kq * 4 + i;
          int col = ch + ct * 16 + lrow;
          float v = acc[ct][i] + bb[ct];
          v = v > 0.f ? v : 0.01f * v;
          st2(Xout, row, col * 2, 256, f2bf(v));
        }
      unsigned char* t = Xin; Xin = Xout; Xout = t;
    } else {
#pragma unroll
      for (int ct = 0; ct < 4; ct++)
#pragma unroll
        for (int i = 0; i < 4; i++) {
          int row = rh + kq * 4 + i;
          int col = ch + ct * 16 + lrow;
          float v = acc[ct][i] + bb[ct];
          size_t gi = (size_t)(r0 + row) * DN + col;
          all_emb[gi] = v;
          embs_sum[gi] += v;
        }
    }
    cw ^= 1;
  }
}

// fused: pre = (users@items^T)*mask; partial[blk] = sum(w*|pre - tq|)
__global__ __launch_bounds__(256) void k_loss(const unsigned short* __restrict__ sbf,
                                              const float* __restrict__ tq,
                                              const float* __restrict__ lw,
                                              const int* __restrict__ msk,
                                              float* __restrict__ partial) {
  const unsigned short* ubf = sbf;
  const unsigned short* ibf = sbf + (size_t)UN * DN;
  const int r0 = blockIdx.x * 32;
  const int c0 = blockIdx.y * 128;
  const int tid = threadIdx.x;
  const int wave = tid >> 6, lane = tid & 63;
  const int wr = (wave >> 1) * 16;
  const int wc = (wave & 1) * 64;
  const int lrow = lane & 15;
  const int kgrp = (lane >> 4) * 8;

  f32x4 acc[4];
#pragma unroll
  for (int i = 0; i < 4; i++) acc[i] = (f32x4){0.f, 0.f, 0.f, 0.f};
#pragma unroll
  for (int kk = 0; kk < 128; kk += 32) {
    bf16x8 af = *(const bf16x8*)(ubf + (size_t)(r0 + wr + lrow) * DN + kk + kgrp);
#pragma unroll
    for (int ct = 0; ct < 4; ct++) {
      bf16x8 bf = *(const bf16x8*)(ibf + (size_t)(c0 + wc + ct * 16 + lrow) * DN + kk + kgrp);
      acc[ct] = __builtin_amdgcn_mfma_f32_16x16x32_bf16(af, bf, acc[ct], 0, 0, 0);
    }
  }
  float lsum = 0.f;
#pragma unroll
  for (int ct = 0; ct < 4; ct++)
#pragma unroll
    for (int i = 0; i < 4; i++) {
      int r = r0 + wr + (lane >> 4) * 4 + i;
      int c = c0 + wc + ct * 16 + lrow;
      size_t gi = (size_t)r * SN + c;
      float pre = msk[gi] ? acc[ct][i] : 0.f;
      lsum += lw[gi] * fabsf(pre - tq[gi]);
    }
  __shared__ float red[256];
  red[tid] = lsum;
  __syncthreads();
  for (int st = 128; st > 0; st >>= 1) {
    if (tid < st) red[tid] += red[tid + st];
    __syncthreads();
  }
  if (tid == 0) partial[blockIdx.x * 64 + blockIdx.y] = red[0];
}

__global__ void k_reduce(const float* __restrict__ p, float* __restrict__ out) {
  __shared__ float red[256];
  float s = 0.f;
  for (int i = threadIdx.x; i < 4096; i += 256) s += p[i];
  red[threadIdx.x] = s;
  __syncthreads();
  for (int st = 128; st > 0; st >>= 1) {
    if (threadIdx.x < st) red[threadIdx.x] += red[threadIdx.x + st];
    __syncthreads();
  }
  if (threadIdx.x == 0) out[0] = red[0];
}

extern "C" void kernel_launch(void* const* d_in, const int* in_sizes, int n_in,
                              void* d_out, int out_size, void* d_ws, size_t ws_size,
                              hipStream_t stream) {
  const float* user_emb = (const float*)d_in[0];
  const float* item_emb = (const float*)d_in[1];
  const float* grpha    = (const float*)d_in[2];
  const float* W1 = (const float*)d_in[3];
  const float* b1 = (const float*)d_in[4];
  const float* W2 = (const float*)d_in[5];
  const float* b2 = (const float*)d_in[6];
  const float* W3 = (const float*)d_in[7];
  const float* b3 = (const float*)d_in[8];
  const float* tq = (const float*)d_in[9];
  const float* lw = (const float*)d_in[10];
  const int* msk  = (const int*)d_in[11];
  float* out = (float*)d_out;

  char* ws = (char*)d_ws;
  unsigned char* A8 = (unsigned char*)ws;        ws += (size_t)NA * NA;             // 105 MB
  float* all_emb  = (float*)ws;                  ws += (size_t)NA * DN * 4;
  float* embs_sum = (float*)ws;                  ws += (size_t)NA * DN * 4;
  unsigned short* part = (unsigned short*)ws;    ws += (size_t)SPLITS * NA * DN * 2; // 21 MB
  unsigned char* Bt8 = (unsigned char*)ws;       ws += (size_t)DN * NA;             // 1.3 MB
  unsigned short* sbf = (unsigned short*)ws;     ws += (size_t)NA * DN * 2;
  unsigned short* wbf = (unsigned short*)ws;     ws += (size_t)3 * DN * DN * 2;
  float* lpart    = (float*)ws;                  ws += 4096 * 4;

  k_cvt8<<<(NA * NA / 16) / 256, 256, 0, stream>>>(grpha, A8);
  k_init<<<1280, 256, 0, stream>>>((const float4*)user_emb, (const float4*)item_emb,
                                   (float4*)all_emb, (float4*)embs_sum);
  k_wcvt<<<24, 256, 0, stream>>>(W1, W2, W3, wbf);
  for (int layer = 0; layer < 3; layer++) {
    k_bt8<<<320, 256, 0, stream>>>(all_emb, Bt8);
    k_gemm<<<dim3(SPLITS, NA / 128), 256, 0, stream>>>(A8, Bt8, part);
    float scale = 1.0f / ((1.0f + (float)layer) * 4194304.0f);  // /(1+l)/4096/1024
    k_transform<<<320, 256, 0, stream>>>(part, scale, wbf, b1, b2, b3, all_emb, embs_sum);
  }
  k_cvt<<<(NA * DN / 8) / 256, 256, 0, stream>>>(embs_sum, sbf);
  k_loss<<<dim3(64, 64), 256, 0, stream>>>(sbf, tq, lw, msk, lpart);
  k_reduce<<<1, 256, 0, stream>>>(lpart, out);
}

// Round 5
// 343.885 us; speedup vs baseline: 1.6629x; 1.0661x over previous
//
#include <hip/hip_runtime.h>
#include <hip/hip_bf16.h>

#define UN 2048
#define SN 8192
#define NA 10240
#define DN 128
#define SPLITS 8
#define KSPL (NA / SPLITS)  // 1280
#define BK 128
#define KT (KSPL / BK)      // 10

typedef __attribute__((ext_vector_type(8))) short bf16x8;
typedef __attribute__((ext_vector_type(4))) float f32x4;
typedef __attribute__((ext_vector_type(8))) int i32x8;

#if __has_builtin(__builtin_amdgcn_mfma_scale_f32_16x16x128_f8f6f4)
#define HAVE_MX 1
#else
#define HAVE_MX 0
#endif

__device__ __forceinline__ unsigned short f2bf(float f) {
  unsigned int u = __builtin_bit_cast(unsigned int, f);
  u += 0x7fffu + ((u >> 16) & 1u);
  return (unsigned short)(u >> 16);
}
__device__ __forceinline__ unsigned int pk2(float a, float b) {
  return (unsigned int)f2bf(a) | ((unsigned int)f2bf(b) << 16);
}

// ---- fp8 e4m3fn packing (scaled upstream) ----
#if __has_builtin(__builtin_amdgcn_cvt_pk_fp8_f32)
__device__ __forceinline__ unsigned int pkfp8_4(float a, float b, float c, float d) {
  int w = __builtin_amdgcn_cvt_pk_fp8_f32(a, b, 0, false);
  w = __builtin_amdgcn_cvt_pk_fp8_f32(c, d, w, true);
  return (unsigned int)w;
}
#else
__device__ __forceinline__ unsigned char f2e4m3(float f) {
  unsigned int u = __builtin_bit_cast(unsigned int, f);
  unsigned int s = (u >> 24) & 0x80u;
  unsigned int a = u & 0x7fffffffu;
  if (a < 0x3c800000u) return (unsigned char)s;
  if (a > 0x43e00000u) a = 0x43e00000u;
  a += 0x7ffffu + ((a >> 20) & 1u);
  unsigned int e = (a >> 23) - 120u;
  unsigned int m = (a >> 20) & 7u;
  if (e > 15u) { e = 15u; m = 6u; }
  return (unsigned char)(s | (e << 3) | m);
}
__device__ __forceinline__ unsigned int pkfp8_4(float a, float b, float c, float d) {
  return (unsigned int)f2e4m3(a) | ((unsigned int)f2e4m3(b) << 8) |
         ((unsigned int)f2e4m3(c) << 16) | ((unsigned int)f2e4m3(d) << 24);
}
#endif

// async global->LDS, 16B per lane
__device__ __forceinline__ void gl_lds16(const void* g, void* l) {
  __builtin_amdgcn_global_load_lds((const __attribute__((address_space(1))) unsigned int*)g,
                                   (__attribute__((address_space(3))) unsigned int*)l, 16, 0, 0);
}
// swizzled LDS helpers (bf16 tiles in k_transform)
__device__ __forceinline__ void st16(unsigned char* base, int row, int cb, int stride, uint4 v) {
  int off = row * stride + cb;
  off ^= (row & 7) << 4;
  *(uint4*)(base + off) = v;
}
__device__ __forceinline__ bf16x8 ld16(const unsigned char* base, int row, int cb, int stride) {
  int off = row * stride + cb;
  off ^= (row & 7) << 4;
  return *(const bf16x8*)(base + off);
}
__device__ __forceinline__ void st2(unsigned char* base, int row, int cb, int stride, unsigned short h) {
  int off = row * stride + cb;
  off ^= (row & 7) << 4;
  *(unsigned short*)(base + off) = h;
}

// all_emb = concat(user_emb, item_emb); embs_sum = all_emb
__global__ void k_init(const float4* __restrict__ ue, const float4* __restrict__ ie,
                       float4* __restrict__ ae, float4* __restrict__ es) {
  int i = blockIdx.x * 256 + threadIdx.x;
  float4 v = (i < UN * DN / 4) ? ue[i] : ie[i - UN * DN / 4];
  ae[i] = v;
  es[i] = v;
}

// fp8 image layout (both A8 and Bt8): within each 128-k block of row r, logical
// granule g (16 consecutive k) is stored at byte position (g ^ (r&7))*16.
// all_emb fp32 -> Bt8 fp8 (x1024), transposed into that image.
__global__ void k_bt8(const float* __restrict__ emb, unsigned char* __restrict__ bt) {
  int t = blockIdx.x * 256 + threadIdx.x;  // 81920 granules
  int c = t & 127;
  int w = t >> 7;            // 0..639
  int kb = w >> 3, g = w & 7;
  const int kbase = kb * 128 + g * 16;
  float v[16];
#pragma unroll
  for (int j = 0; j < 16; j++) v[j] = emb[(size_t)(kbase + j) * DN + c];
  const float S = 1024.f;
  uint4 o;
  o.x = pkfp8_4(v[0] * S, v[1] * S, v[2] * S, v[3] * S);
  o.y = pkfp8_4(v[4] * S, v[5] * S, v[6] * S, v[7] * S);
  o.z = pkfp8_4(v[8] * S, v[9] * S, v[10] * S, v[11] * S);
  o.w = pkfp8_4(v[12] * S, v[13] * S, v[14] * S, v[15] * S);
  *(uint4*)(bt + (size_t)c * NA + kb * 128 + ((g ^ (c & 7)) * 16)) = o;
}

// embs_sum fp32 -> bf16 stream
__global__ void k_cvt(const float* __restrict__ x, unsigned short* __restrict__ y) {
  size_t i = (size_t)blockIdx.x * 256 + threadIdx.x;
  const float4* p = (const float4*)(x + i * 8);
  float4 a = p[0], b = p[1];
  uint4 w;
  w.x = pk2(a.x, a.y); w.y = pk2(a.z, a.w);
  w.z = pk2(b.x, b.y); w.w = pk2(b.z, b.w);
  ((uint4*)y)[i] = w;
}

// W1,W2,W3 -> bf16, pre-swizzled for gl_lds16 + ld16
__global__ void k_wcvt(const float* __restrict__ W1, const float* __restrict__ W2,
                       const float* __restrict__ W3, unsigned short* __restrict__ wbf) {
  int g = blockIdx.x * 256 + threadIdx.x;
  int mat = g / 2048;
  int idx = g % 2048;
  int r = idx / 16, cg = idx % 16;
  const float* Wp = (mat == 0) ? W1 : (mat == 1) ? W2 : W3;
  const float4* src = (const float4*)(Wp + (size_t)r * DN + cg * 8);
  float4 a = src[0], b = src[1];
  uint4 w;
  w.x = pk2(a.x, a.y); w.y = pk2(a.z, a.w);
  w.z = pk2(b.x, b.y); w.w = pk2(b.z, b.w);
  *(uint4*)(wbf + (size_t)mat * 16384 + r * 128 + ((cg ^ (r & 7)) * 8)) = w;
}

// part[ks] = A[:, ks-chunk] @ Bt[ks-chunk]^T  (fp8 MX MFMA K=128, bf16 part out)
// MODE 0: A8 image via gl_lds16.  MODE 1: fp32 A -> reg-stage fp8 + write A8 image.
template <int MODE>
__global__ __launch_bounds__(256, 2) void k_gemm(const float* __restrict__ Af,
                                                 unsigned char* __restrict__ A8,
                                                 const unsigned char* __restrict__ B8,
                                                 unsigned short* __restrict__ part) {
  __shared__ __align__(16) unsigned char As[2][128 * 128];  // 2 x 16 KB
  __shared__ __align__(16) unsigned char Bs[2][128 * 128];  // 2 x 16 KB
  const int ks = blockIdx.x;
  const int m0 = blockIdx.y * 128;
  const int k0 = ks * KSPL;  // elements == bytes in fp8 image
  const int tid = threadIdx.x;
  const int wave = tid >> 6, lane = tid & 63;
  const int lrow = lane & 15;
  const int kq = lane >> 4;          // 0..3
  const int wr = (wave >> 1) * 64;
  const int wc = (wave & 1) * 64;
  const int rx = lrow & 7;           // fragment-row swizzle key

  auto stage = [&](int buf, int kt) {
    const int kg = k0 + kt * BK;
#pragma unroll
    for (int j = 0; j < 4; j++) {
      const int L = j * 256 + tid;   // granule 0..1023
      const int row = L >> 3, p = L & 7;
      gl_lds16(B8 + (size_t)row * NA + kg + p * 16, (char*)Bs[buf] + L * 16);
    }
#pragma unroll
    for (int j = 0; j < 4; j++) {
      const int L = j * 256 + tid;
      const int row = L >> 3, p = L & 7;
      if (MODE == 0) {
        gl_lds16(A8 + (size_t)(m0 + row) * NA + kg + p * 16, (char*)As[buf] + L * 16);
      } else {
        const int g = p ^ (row & 7);
        const float* src = Af + (size_t)(m0 + row) * NA + kg + g * 16;
        float4 f0 = *(const float4*)src;
        float4 f1 = *(const float4*)(src + 4);
        float4 f2 = *(const float4*)(src + 8);
        float4 f3 = *(const float4*)(src + 12);
        const float S = 4096.f;
        uint4 v;
        v.x = pkfp8_4(f0.x * S, f0.y * S, f0.z * S, f0.w * S);
        v.y = pkfp8_4(f1.x * S, f1.y * S, f1.z * S, f1.w * S);
        v.z = pkfp8_4(f2.x * S, f2.y * S, f2.z * S, f2.w * S);
        v.w = pkfp8_4(f3.x * S, f3.y * S, f3.z * S, f3.w * S);
        *(uint4*)((char*)As[buf] + L * 16) = v;
        *(uint4*)(A8 + (size_t)(m0 + row) * NA + kg + p * 16) = v;
      }
    }
  };

  f32x4 acc[4][4];  // [fj][fi]
#pragma unroll
  for (int fj = 0; fj < 4; fj++)
#pragma unroll
    for (int fi = 0; fi < 4; fi++) acc[fj][fi] = (f32x4){0.f, 0.f, 0.f, 0.f};

  stage(0, 0);
  int cur = 0;
  for (int kt = 0; kt < KT; kt++) {
    __syncthreads();  // buf[cur] staged (vmcnt+lgkm drained); prior reads done
    if (kt + 1 < KT) stage(cur ^ 1, kt + 1);  // prefetch overlaps compute

#if HAVE_MX
    i32x8 av[4], bv[4];
#pragma unroll
    for (int fi = 0; fi < 4; fi++) {
      const unsigned char* ab = As[cur] + (wr + fi * 16 + lrow) * 128;
      uint4 lo = *(const uint4*)(ab + (((2 * kq) ^ rx) << 4));
      uint4 hi = *(const uint4*)(ab + (((2 * kq + 1) ^ rx) << 4));
      i32x8 a; a[0] = lo.x; a[1] = lo.y; a[2] = lo.z; a[3] = lo.w;
      a[4] = hi.x; a[5] = hi.y; a[6] = hi.z; a[7] = hi.w;
      av[fi] = a;
    }
#pragma unroll
    for (int fj = 0; fj < 4; fj++) {
      const unsigned char* bb = Bs[cur] + (wc + fj * 16 + lrow) * 128;
      uint4 lo = *(const uint4*)(bb + (((2 * kq) ^ rx) << 4));
      uint4 hi = *(const uint4*)(bb + (((2 * kq + 1) ^ rx) << 4));
      i32x8 b; b[0] = lo.x; b[1] = lo.y; b[2] = lo.z; b[3] = lo.w;
      b[4] = hi.x; b[5] = hi.y; b[6] = hi.z; b[7] = hi.w;
      bv[fj] = b;
    }
#pragma unroll
    for (int fj = 0; fj < 4; fj++)
#pragma unroll
      for (int fi = 0; fi < 4; fi++)
        acc[fj][fi] = __builtin_amdgcn_mfma_scale_f32_16x16x128_f8f6f4(
            bv[fj], av[fi], acc[fj][fi], 0, 0, 0, 0x7f7f7f7f, 0, 0x7f7f7f7f);
#else
    // fallback: 4x 16x16x32 fp8 on the same LDS image (k = s*32 + kq*8 + [0..8))
#pragma unroll
    for (int s = 0; s < 4; s++) {
      const int G = 2 * s + (kq >> 1);
      const int boff = ((G ^ rx) << 4) + (kq & 1) * 8;
      long a[4], b[4];
#pragma unroll
      for (int fi = 0; fi < 4; fi++)
        a[fi] = *(const long*)(As[cur] + (wr + fi * 16 + lrow) * 128 + boff);
#pragma unroll
      for (int fj = 0; fj < 4; fj++)
        b[fj] = *(const long*)(Bs[cur] + (wc + fj * 16 + lrow) * 128 + boff);
#pragma unroll
      for (int fj = 0; fj < 4; fj++)
#pragma unroll
        for (int fi = 0; fi < 4; fi++)
          acc[fj][fi] = __builtin_amdgcn_mfma_f32_16x16x32_fp8_fp8(b[fj], a[fi], acc[fj][fi], 0, 0, 0);
    }
#endif
    cur ^= 1;
  }

  // operand-swapped D: lane holds 4 consecutive n at row m
  unsigned short* op = part + (size_t)ks * NA * DN;
#pragma unroll
  for (int fi = 0; fi < 4; fi++) {
    const size_t mrow = (size_t)(m0 + wr + fi * 16 + lrow) * DN;
#pragma unroll
    for (int fj = 0; fj < 4; fj++) {
      const int n = wc + fj * 16 + kq * 4;
      uint2 pkd;
      pkd.x = pk2(acc[fj][fi][0], acc[fj][fi][1]);
      pkd.y = pk2(acc[fj][fi][2], acc[fj][fi][3]);
      *(uint2*)(op + mrow + n) = pkd;
    }
  }
}

// x = (sum of SPLITS bf16 partials)*scale; 3-layer MLP; all_emb = x; embs_sum += x
__global__ __launch_bounds__(256) void k_transform(
    const unsigned short* __restrict__ part, float scale,
    const unsigned short* __restrict__ wbf,
    const float* __restrict__ b1, const float* __restrict__ b2, const float* __restrict__ b3,
    float* __restrict__ all_emb, float* __restrict__ embs_sum) {
  __shared__ __align__(16) unsigned char Ws[2][128 * 128 * 2];  // 2 x 32 KB
  __shared__ __align__(16) unsigned char Xa[32 * 128 * 2];      // 8 KB
  __shared__ __align__(16) unsigned char Xb[32 * 128 * 2];      // 8 KB
  const int r0 = blockIdx.x * 32;
  const int tid = threadIdx.x;
  const int wave = tid >> 6, lane = tid & 63;
  const int lrow = lane & 15;
  const int kq = lane >> 4;
  const int kgrp = kq * 8;
  const int rh = (wave & 1) * 16;
  const int ch = (wave >> 1) * 64;

  auto stage_W = [&](int buf, int s) {
#pragma unroll
    for (int j = 0; j < 8; j++) {
      const int L = j * 256 + tid;
      gl_lds16(wbf + (size_t)s * 16384 + L * 8, (char*)Ws[buf] + L * 16);
    }
  };

  stage_W(0, 0);
  {  // stage input tile into Xa: sum 8 bf16 slabs -> fp32 -> scale -> bf16
    const int xr = tid >> 3, xc = (tid & 7) * 16;
    const size_t base = (size_t)(r0 + xr) * DN + xc;
    float xs[16];
#pragma unroll
    for (int q = 0; q < 16; q++) xs[q] = 0.f;
#pragma unroll
    for (int s = 0; s < SPLITS; s++) {
      const unsigned short* p = part + (size_t)s * NA * DN + base;
      uint4 w1 = *(const uint4*)p;
      uint4 w2 = *(const uint4*)(p + 8);
      const unsigned int wsv[8] = {w1.x, w1.y, w1.z, w1.w, w2.x, w2.y, w2.z, w2.w};
#pragma unroll
      for (int q = 0; q < 8; q++) {
        xs[2 * q]     += __builtin_bit_cast(float, wsv[q] << 16);
        xs[2 * q + 1] += __builtin_bit_cast(float, wsv[q] & 0xffff0000u);
      }
    }
    uint4 w;
    w.x = pk2(xs[0] * scale, xs[1] * scale);   w.y = pk2(xs[2] * scale, xs[3] * scale);
    w.z = pk2(xs[4] * scale, xs[5] * scale);   w.w = pk2(xs[6] * scale, xs[7] * scale);
    st16(Xa, xr, xc * 2, 256, w);
    w.x = pk2(xs[8] * scale, xs[9] * scale);   w.y = pk2(xs[10] * scale, xs[11] * scale);
    w.z = pk2(xs[12] * scale, xs[13] * scale); w.w = pk2(xs[14] * scale, xs[15] * scale);
    st16(Xa, xr, (xc + 8) * 2, 256, w);
  }

  const float* bp[3] = {b1, b2, b3};
  unsigned char* Xin = Xa;
  unsigned char* Xout = Xb;
  int cw = 0;

  for (int s = 0; s < 3; s++) {
    __syncthreads();
    if (s < 2) stage_W(cw ^ 1, s + 1);
    float bb[4];
#pragma unroll
    for (int ct = 0; ct < 4; ct++) bb[ct] = bp[s][ch + ct * 16 + lrow];

    f32x4 acc[4];
#pragma unroll
    for (int i = 0; i < 4; i++) acc[i] = (f32x4){0.f, 0.f, 0.f, 0.f};
#pragma unroll
    for (int kk = 0; kk < 128; kk += 32) {
      bf16x8 af = ld16(Xin, rh + lrow, (kk + kgrp) * 2, 256);
#pragma unroll
      for (int ct = 0; ct < 4; ct++) {
        bf16x8 bf = ld16(Ws[cw], ch + ct * 16 + lrow, (kk + kgrp) * 2, 256);
        acc[ct] = __builtin_amdgcn_mfma_f32_16x16x32_bf16(af, bf, acc[ct], 0, 0, 0);
      }
    }

    if (s < 2) {
#pragma unroll
      for (int ct = 0; ct < 4; ct++)
#pragma unroll
        for (int i = 0; i < 4; i++) {
          int row = rh + kq * 4 + i;
          int col = ch + ct * 16 + lrow;
          float v = acc[ct][i] + bb[ct];
          v = v > 0.f ? v : 0.01f * v;
          st2(Xout, row, col * 2, 256, f2bf(v));
        }
      unsigned char* t = Xin; Xin = Xout; Xout = t;
    } else {
#pragma unroll
      for (int ct = 0; ct < 4; ct++)
#pragma unroll
        for (int i = 0; i < 4; i++) {
          int row = rh + kq * 4 + i;
          int col = ch + ct * 16 + lrow;
          float v = acc[ct][i] + bb[ct];
          size_t gi = (size_t)(r0 + row) * DN + col;
          all_emb[gi] = v;
          embs_sum[gi] += v;
        }
    }
    cw ^= 1;
  }
}

// fused: pre = (users@items^T)*mask; partial[blk] = sum(w*|pre - tq|)
__global__ __launch_bounds__(256) void k_loss(const unsigned short* __restrict__ sbf,
                                              const float* __restrict__ tq,
                                              const float* __restrict__ lw,
                                              const int* __restrict__ msk,
                                              float* __restrict__ partial) {
  const unsigned short* ubf = sbf;
  const unsigned short* ibf = sbf + (size_t)UN * DN;
  const int r0 = blockIdx.x * 32;
  const int c0 = blockIdx.y * 128;
  const int tid = threadIdx.x;
  const int wave = tid >> 6, lane = tid & 63;
  const int wr = (wave >> 1) * 16;
  const int wc = (wave & 1) * 64;
  const int lrow = lane & 15;
  const int kgrp = (lane >> 4) * 8;

  f32x4 acc[4];
#pragma unroll
  for (int i = 0; i < 4; i++) acc[i] = (f32x4){0.f, 0.f, 0.f, 0.f};
#pragma unroll
  for (int kk = 0; kk < 128; kk += 32) {
    bf16x8 af = *(const bf16x8*)(ubf + (size_t)(r0 + wr + lrow) * DN + kk + kgrp);
#pragma unroll
    for (int ct = 0; ct < 4; ct++) {
      bf16x8 bf = *(const bf16x8*)(ibf + (size_t)(c0 + wc + ct * 16 + lrow) * DN + kk + kgrp);
      acc[ct] = __builtin_amdgcn_mfma_f32_16x16x32_bf16(af, bf, acc[ct], 0, 0, 0);
    }
  }
  float lsum = 0.f;
#pragma unroll
  for (int ct = 0; ct < 4; ct++)
#pragma unroll
    for (int i = 0; i < 4; i++) {
      int r = r0 + wr + (lane >> 4) * 4 + i;
      int c = c0 + wc + ct * 16 + lrow;
      size_t gi = (size_t)r * SN + c;
      float pre = msk[gi] ? acc[ct][i] : 0.f;
      lsum += lw[gi] * fabsf(pre - tq[gi]);
    }
  __shared__ float red[256];
  red[tid] = lsum;
  __syncthreads();
  for (int st = 128; st > 0; st >>= 1) {
    if (tid < st) red[tid] += red[tid + st];
    __syncthreads();
  }
  if (tid == 0) partial[blockIdx.x * 64 + blockIdx.y] = red[0];
}

__global__ void k_reduce(const float* __restrict__ p, float* __restrict__ out) {
  __shared__ float red[256];
  float s = 0.f;
  for (int i = threadIdx.x; i < 4096; i += 256) s += p[i];
  red[threadIdx.x] = s;
  __syncthreads();
  for (int st = 128; st > 0; st >>= 1) {
    if (threadIdx.x < st) red[threadIdx.x] += red[threadIdx.x + st];
    __syncthreads();
  }
  if (threadIdx.x == 0) out[0] = red[0];
}

extern "C" void kernel_launch(void* const* d_in, const int* in_sizes, int n_in,
                              void* d_out, int out_size, void* d_ws, size_t ws_size,
                              hipStream_t stream) {
  const float* user_emb = (const float*)d_in[0];
  const float* item_emb = (const float*)d_in[1];
  const float* grpha    = (const float*)d_in[2];
  const float* W1 = (const float*)d_in[3];
  const float* b1 = (const float*)d_in[4];
  const float* W2 = (const float*)d_in[5];
  const float* b2 = (const float*)d_in[6];
  const float* W3 = (const float*)d_in[7];
  const float* b3 = (const float*)d_in[8];
  const float* tq = (const float*)d_in[9];
  const float* lw = (const float*)d_in[10];
  const int* msk  = (const int*)d_in[11];
  float* out = (float*)d_out;

  char* ws = (char*)d_ws;
  unsigned char* A8 = (unsigned char*)ws;        ws += (size_t)NA * NA;              // 105 MB
  float* all_emb  = (float*)ws;                  ws += (size_t)NA * DN * 4;
  float* embs_sum = (float*)ws;                  ws += (size_t)NA * DN * 4;
  unsigned short* part = (unsigned short*)ws;    ws += (size_t)SPLITS * NA * DN * 2; // 21 MB
  unsigned char* Bt8 = (unsigned char*)ws;       ws += (size_t)DN * NA;              // 1.3 MB
  unsigned short* sbf = (unsigned short*)ws;     ws += (size_t)NA * DN * 2;
  unsigned short* wbf = (unsigned short*)ws;     ws += (size_t)3 * DN * DN * 2;
  float* lpart    = (float*)ws;                  ws += 4096 * 4;

  k_init<<<1280, 256, 0, stream>>>((const float4*)user_emb, (const float4*)item_emb,
                                   (float4*)all_emb, (float4*)embs_sum);
  k_wcvt<<<24, 256, 0, stream>>>(W1, W2, W3, wbf);
  for (int layer = 0; layer < 3; layer++) {
    k_bt8<<<320, 256, 0, stream>>>(all_emb, Bt8);
    if (layer == 0)
      k_gemm<1><<<dim3(SPLITS, NA / 128), 256, 0, stream>>>(grpha, A8, Bt8, part);
    else
      k_gemm<0><<<dim3(SPLITS, NA / 128), 256, 0, stream>>>(grpha, A8, Bt8, part);
    float scale = 1.0f / ((1.0f + (float)layer) * 4194304.0f);  // /(1+l)/4096/1024
    k_transform<<<320, 256, 0, stream>>>(part, scale, wbf, b1, b2, b3, all_emb, embs_sum);
  }
  k_cvt<<<(NA * DN / 8) / 256, 256, 0, stream>>>(embs_sum, sbf);
  k_loss<<<dim3(64, 64), 256, 0, stream>>>(sbf, tq, lw, msk, lpart);
  k_reduce<<<1, 256, 0, stream>>>(lpart, out);
}

// Round 6
// 311.745 us; speedup vs baseline: 1.8344x; 1.1031x over previous
//
#include <hip/hip_runtime.h>
#include <hip/hip_bf16.h>

#define UN 2048
#define SN 8192
#define NA 10240
#define DN 128
#define SPLITS 8
#define KSPL (NA / SPLITS)  // 1280
#define BK 128
#define KT (KSPL / BK)      // 10

typedef __attribute__((ext_vector_type(8))) short bf16x8;
typedef __attribute__((ext_vector_type(4))) float f32x4;
typedef __attribute__((ext_vector_type(8))) int i32x8;

#if __has_builtin(__builtin_amdgcn_mfma_scale_f32_16x16x128_f8f6f4)
#define HAVE_MX 1
#else
#define HAVE_MX 0
#endif

__device__ __forceinline__ unsigned short f2bf(float f) {
  unsigned int u = __builtin_bit_cast(unsigned int, f);
  u += 0x7fffu + ((u >> 16) & 1u);
  return (unsigned short)(u >> 16);
}
__device__ __forceinline__ unsigned int pk2(float a, float b) {
  return (unsigned int)f2bf(a) | ((unsigned int)f2bf(b) << 16);
}

// ---- fp8 e4m3fn packing (scaled upstream) ----
#if __has_builtin(__builtin_amdgcn_cvt_pk_fp8_f32)
__device__ __forceinline__ unsigned int pkfp8_4(float a, float b, float c, float d) {
  int w = __builtin_amdgcn_cvt_pk_fp8_f32(a, b, 0, false);
  w = __builtin_amdgcn_cvt_pk_fp8_f32(c, d, w, true);
  return (unsigned int)w;
}
#else
__device__ __forceinline__ unsigned char f2e4m3(float f) {
  unsigned int u = __builtin_bit_cast(unsigned int, f);
  unsigned int s = (u >> 24) & 0x80u;
  unsigned int a = u & 0x7fffffffu;
  if (a < 0x3c800000u) return (unsigned char)s;
  if (a > 0x43e00000u) a = 0x43e00000u;
  a += 0x7ffffu + ((a >> 20) & 1u);
  unsigned int e = (a >> 23) - 120u;
  unsigned int m = (a >> 20) & 7u;
  if (e > 15u) { e = 15u; m = 6u; }
  return (unsigned char)(s | (e << 3) | m);
}
__device__ __forceinline__ unsigned int pkfp8_4(float a, float b, float c, float d) {
  return (unsigned int)f2e4m3(a) | ((unsigned int)f2e4m3(b) << 8) |
         ((unsigned int)f2e4m3(c) << 16) | ((unsigned int)f2e4m3(d) << 24);
}
#endif

// async global->LDS, 16B per lane
__device__ __forceinline__ void gl_lds16(const void* g, void* l) {
  __builtin_amdgcn_global_load_lds((const __attribute__((address_space(1))) unsigned int*)g,
                                   (__attribute__((address_space(3))) unsigned int*)l, 16, 0, 0);
}
// swizzled LDS helpers (bf16 tiles in k_transform)
__device__ __forceinline__ void st16(unsigned char* base, int row, int cb, int stride, uint4 v) {
  int off = row * stride + cb;
  off ^= (row & 7) << 4;
  *(uint4*)(base + off) = v;
}
__device__ __forceinline__ bf16x8 ld16(const unsigned char* base, int row, int cb, int stride) {
  int off = row * stride + cb;
  off ^= (row & 7) << 4;
  return *(const bf16x8*)(base + off);
}
__device__ __forceinline__ void st2(unsigned char* base, int row, int cb, int stride, unsigned short h) {
  int off = row * stride + cb;
  off ^= (row & 7) << 4;
  *(unsigned short*)(base + off) = h;
}

// prep: [0,1280) embs_sum = concat(ue,ie); [1280,1304) wcvt; [1304,1624) Bt8 layer-0.
// fp8 image layout (A8 & Bt8): in each 128-k block of row r, granule g (16 k's)
// stored at byte position (g ^ (r&7))*16.
__global__ void k_prep(const float* __restrict__ ue, const float* __restrict__ ie,
                       const float* __restrict__ W1, const float* __restrict__ W2,
                       const float* __restrict__ W3, float* __restrict__ es,
                       unsigned short* __restrict__ wbf, unsigned char* __restrict__ bt) {
  const int bid = blockIdx.x;
  const int tid = threadIdx.x;
  if (bid < 1280) {
    int i = bid * 256 + tid;  // float4 index over NA*DN/4
    float4 v = (i < UN * DN / 4) ? ((const float4*)ue)[i] : ((const float4*)ie)[i - UN * DN / 4];
    ((float4*)es)[i] = v;
  } else if (bid < 1304) {
    int g = (bid - 1280) * 256 + tid;  // 6144
    int mat = g / 2048;
    int idx = g % 2048;
    int r = idx / 16, cg = idx % 16;
    const float* Wp = (mat == 0) ? W1 : (mat == 1) ? W2 : W3;
    const float4* src = (const float4*)(Wp + (size_t)r * DN + cg * 8);
    float4 a = src[0], b = src[1];
    uint4 w;
    w.x = pk2(a.x, a.y); w.y = pk2(a.z, a.w);
    w.z = pk2(b.x, b.y); w.w = pk2(b.z, b.w);
    *(uint4*)(wbf + (size_t)mat * 16384 + r * 128 + ((cg ^ (r & 7)) * 8)) = w;
  } else {
    int t = (bid - 1304) * 256 + tid;  // 81920 granules
    int c = t & 127;
    int w = t >> 7;
    int kb = w >> 3, g = w & 7;
    const int kbase = kb * 128 + g * 16;
    float v[16];
#pragma unroll
    for (int j = 0; j < 16; j++) {
      int r = kbase + j;
      v[j] = (r < UN) ? ue[(size_t)r * DN + c] : ie[(size_t)(r - UN) * DN + c];
    }
    const float S = 1024.f;
    uint4 o;
    o.x = pkfp8_4(v[0] * S, v[1] * S, v[2] * S, v[3] * S);
    o.y = pkfp8_4(v[4] * S, v[5] * S, v[6] * S, v[7] * S);
    o.z = pkfp8_4(v[8] * S, v[9] * S, v[10] * S, v[11] * S);
    o.w = pkfp8_4(v[12] * S, v[13] * S, v[14] * S, v[15] * S);
    *(uint4*)(bt + (size_t)c * NA + kb * 128 + ((g ^ (c & 7)) * 16)) = o;
  }
}

// part[ks] = A[:, ks-chunk] @ Bt[ks-chunk]^T  (fp8 MX MFMA K=128, bf16 part out)
// MODE 0: A8 via gl_lds16, counted-vmcnt pipeline (T4).
// MODE 1: fp32 A -> reg-stage fp8 + write A8 image; full-drain sync.
template <int MODE>
__global__ __launch_bounds__(256, 2) void k_gemm(const float* __restrict__ Af,
                                                 unsigned char* __restrict__ A8,
                                                 const unsigned char* __restrict__ B8,
                                                 unsigned short* __restrict__ part) {
  __shared__ __align__(16) unsigned char As[2][128 * 128];  // 2 x 16 KB
  __shared__ __align__(16) unsigned char Bs[2][128 * 128];  // 2 x 16 KB
  const int ks = blockIdx.x;
  const int m0 = blockIdx.y * 128;
  const int k0 = ks * KSPL;
  const int tid = threadIdx.x;
  const int wave = tid >> 6, lane = tid & 63;
  const int lrow = lane & 15;
  const int kq = lane >> 4;          // 0..3
  const int wr = (wave >> 1) * 64;
  const int wc = (wave & 1) * 64;
  const int rx = lrow & 7;           // fragment-row swizzle key

  auto stage = [&](int buf, int kt) {
    const int kg = k0 + kt * BK;
#pragma unroll
    for (int j = 0; j < 4; j++) {
      const int L = j * 256 + tid;   // granule 0..1023
      const int row = L >> 3, p = L & 7;
      gl_lds16(B8 + (size_t)row * NA + kg + p * 16, (char*)Bs[buf] + L * 16);
    }
#pragma unroll
    for (int j = 0; j < 4; j++) {
      const int L = j * 256 + tid;
      const int row = L >> 3, p = L & 7;
      if (MODE == 0) {
        gl_lds16(A8 + (size_t)(m0 + row) * NA + kg + p * 16, (char*)As[buf] + L * 16);
      } else {
        const int g = p ^ (row & 7);
        const float* src = Af + (size_t)(m0 + row) * NA + kg + g * 16;
        float4 f0 = *(const float4*)src;
        float4 f1 = *(const float4*)(src + 4);
        float4 f2 = *(const float4*)(src + 8);
        float4 f3 = *(const float4*)(src + 12);
        const float S = 4096.f;
        uint4 v;
        v.x = pkfp8_4(f0.x * S, f0.y * S, f0.z * S, f0.w * S);
        v.y = pkfp8_4(f1.x * S, f1.y * S, f1.z * S, f1.w * S);
        v.z = pkfp8_4(f2.x * S, f2.y * S, f2.z * S, f2.w * S);
        v.w = pkfp8_4(f3.x * S, f3.y * S, f3.z * S, f3.w * S);
        *(uint4*)((char*)As[buf] + L * 16) = v;
        *(uint4*)(A8 + (size_t)(m0 + row) * NA + kg + p * 16) = v;
      }
    }
  };

  f32x4 acc[4][4];  // [fj][fi]
#pragma unroll
  for (int fj = 0; fj < 4; fj++)
#pragma unroll
    for (int fi = 0; fi < 4; fi++) acc[fj][fi] = (f32x4){0.f, 0.f, 0.f, 0.f};

  stage(0, 0);
  int cur = 0;
  for (int kt = 0; kt < KT; kt++) {
    if (MODE == 0) {
      // T4 counted pipeline: barrier A protects buf[cur^1] from overwrite;
      // stage(kt+1) issues BEFORE the wait; vmcnt(8) waits only stage(kt).
      __builtin_amdgcn_s_barrier();
      if (kt + 1 < KT) {
        stage(cur ^ 1, kt + 1);
        asm volatile("s_waitcnt vmcnt(8)" ::: "memory");
      } else {
        asm volatile("s_waitcnt vmcnt(0)" ::: "memory");
      }
      __builtin_amdgcn_s_barrier();  // all waves' stage(kt) writes visible
    } else {
      __syncthreads();  // full drain: buf[cur] staged, prior reads done
      if (kt + 1 < KT) stage(cur ^ 1, kt + 1);
    }

#if HAVE_MX
    i32x8 av[4], bv[4];
#pragma unroll
    for (int fi = 0; fi < 4; fi++) {
      const unsigned char* ab = As[cur] + (wr + fi * 16 + lrow) * 128;
      uint4 lo = *(const uint4*)(ab + (((2 * kq) ^ rx) << 4));
      uint4 hi = *(const uint4*)(ab + (((2 * kq + 1) ^ rx) << 4));
      i32x8 a; a[0] = lo.x; a[1] = lo.y; a[2] = lo.z; a[3] = lo.w;
      a[4] = hi.x; a[5] = hi.y; a[6] = hi.z; a[7] = hi.w;
      av[fi] = a;
    }
#pragma unroll
    for (int fj = 0; fj < 4; fj++) {
      const unsigned char* bb = Bs[cur] + (wc + fj * 16 + lrow) * 128;
      uint4 lo = *(const uint4*)(bb + (((2 * kq) ^ rx) << 4));
      uint4 hi = *(const uint4*)(bb + (((2 * kq + 1) ^ rx) << 4));
      i32x8 b; b[0] = lo.x; b[1] = lo.y; b[2] = lo.z; b[3] = lo.w;
      b[4] = hi.x; b[5] = hi.y; b[6] = hi.z; b[7] = hi.w;
      bv[fj] = b;
    }
#pragma unroll
    for (int fj = 0; fj < 4; fj++)
#pragma unroll
      for (int fi = 0; fi < 4; fi++)
        acc[fj][fi] = __builtin_amdgcn_mfma_scale_f32_16x16x128_f8f6f4(
            bv[fj], av[fi], acc[fj][fi], 0, 0, 0, 0x7f7f7f7f, 0, 0x7f7f7f7f);
#else
#pragma unroll
    for (int s = 0; s < 4; s++) {
      const int G = 2 * s + (kq >> 1);
      const int boff = ((G ^ rx) << 4) + (kq & 1) * 8;
      long a[4], b[4];
#pragma unroll
      for (int fi = 0; fi < 4; fi++)
        a[fi] = *(const long*)(As[cur] + (wr + fi * 16 + lrow) * 128 + boff);
#pragma unroll
      for (int fj = 0; fj < 4; fj++)
        b[fj] = *(const long*)(Bs[cur] + (wc + fj * 16 + lrow) * 128 + boff);
#pragma unroll
      for (int fj = 0; fj < 4; fj++)
#pragma unroll
        for (int fi = 0; fi < 4; fi++)
          acc[fj][fi] = __builtin_amdgcn_mfma_f32_16x16x32_fp8_fp8(b[fj], a[fi], acc[fj][fi], 0, 0, 0);
    }
#endif
    cur ^= 1;
  }

  // operand-swapped D: lane holds 4 consecutive n at row m
  unsigned short* op = part + (size_t)ks * NA * DN;
#pragma unroll
  for (int fi = 0; fi < 4; fi++) {
    const size_t mrow = (size_t)(m0 + wr + fi * 16 + lrow) * DN;
#pragma unroll
    for (int fj = 0; fj < 4; fj++) {
      const int n = wc + fj * 16 + kq * 4;
      uint2 pkd;
      pkd.x = pk2(acc[fj][fi][0], acc[fj][fi][1]);
      pkd.y = pk2(acc[fj][fi][2], acc[fj][fi][3]);
      *(uint2*)(op + mrow + n) = pkd;
    }
  }
}

// x = (sum of SPLITS bf16 partials)*scale; 3-layer MLP.
// LAST=0: embs_sum += x, write Bt8 image for next layer.
// LAST=1: sbf = bf16(embs_sum + x)   (final, no Bt8)
template <int LAST>
__global__ __launch_bounds__(256) void k_transform(
    const unsigned short* __restrict__ part, float scale,
    const unsigned short* __restrict__ wbf,
    const float* __restrict__ b1, const float* __restrict__ b2, const float* __restrict__ b3,
    float* __restrict__ embs_sum, unsigned char* __restrict__ bt_next,
    unsigned short* __restrict__ sbf) {
  __shared__ __align__(16) unsigned char Ws[2][128 * 128 * 2];  // 2 x 32 KB
  __shared__ __align__(16) unsigned char Xa[32 * 128 * 2];      // 8 KB
  __shared__ __align__(16) unsigned char Xb[32 * 128 * 2];      // 8 KB
  const int r0 = blockIdx.x * 32;
  const int tid = threadIdx.x;
  const int wave = tid >> 6, lane = tid & 63;
  const int lrow = lane & 15;
  const int kq = lane >> 4;
  const int kgrp = kq * 8;
  const int rh = (wave & 1) * 16;
  const int ch = (wave >> 1) * 64;

  auto stage_W = [&](int buf, int s) {
#pragma unroll
    for (int j = 0; j < 8; j++) {
      const int L = j * 256 + tid;
      gl_lds16(wbf + (size_t)s * 16384 + L * 8, (char*)Ws[buf] + L * 16);
    }
  };

  stage_W(0, 0);
  {  // stage input tile into Xa: sum 8 bf16 slabs -> fp32 -> scale -> bf16
    const int xr = tid >> 3, xc = (tid & 7) * 16;
    const size_t base = (size_t)(r0 + xr) * DN + xc;
    float xs[16];
#pragma unroll
    for (int q = 0; q < 16; q++) xs[q] = 0.f;
#pragma unroll
    for (int s = 0; s < SPLITS; s++) {
      const unsigned short* p = part + (size_t)s * NA * DN + base;
      uint4 w1 = *(const uint4*)p;
      uint4 w2 = *(const uint4*)(p + 8);
      const unsigned int wsv[8] = {w1.x, w1.y, w1.z, w1.w, w2.x, w2.y, w2.z, w2.w};
#pragma unroll
      for (int q = 0; q < 8; q++) {
        xs[2 * q]     += __builtin_bit_cast(float, wsv[q] << 16);
        xs[2 * q + 1] += __builtin_bit_cast(float, wsv[q] & 0xffff0000u);
      }
    }
    uint4 w;
    w.x = pk2(xs[0] * scale, xs[1] * scale);   w.y = pk2(xs[2] * scale, xs[3] * scale);
    w.z = pk2(xs[4] * scale, xs[5] * scale);   w.w = pk2(xs[6] * scale, xs[7] * scale);
    st16(Xa, xr, xc * 2, 256, w);
    w.x = pk2(xs[8] * scale, xs[9] * scale);   w.y = pk2(xs[10] * scale, xs[11] * scale);
    w.z = pk2(xs[12] * scale, xs[13] * scale); w.w = pk2(xs[14] * scale, xs[15] * scale);
    st16(Xa, xr, (xc + 8) * 2, 256, w);
  }

  const float* bp[3] = {b1, b2, b3};
  unsigned char* Xin = Xa;
  unsigned char* Xout = Xb;
  int cw = 0;

  for (int s = 0; s < 3; s++) {
    __syncthreads();
    if (s < 2) stage_W(cw ^ 1, s + 1);
    float bb[4];
#pragma unroll
    for (int ct = 0; ct < 4; ct++) bb[ct] = bp[s][ch + ct * 16 + lrow];

    f32x4 acc[4];
#pragma unroll
    for (int i = 0; i < 4; i++) acc[i] = (f32x4){0.f, 0.f, 0.f, 0.f};
#pragma unroll
    for (int kk = 0; kk < 128; kk += 32) {
      bf16x8 af = ld16(Xin, rh + lrow, (kk + kgrp) * 2, 256);
#pragma unroll
      for (int ct = 0; ct < 4; ct++) {
        bf16x8 bf = ld16(Ws[cw], ch + ct * 16 + lrow, (kk + kgrp) * 2, 256);
        acc[ct] = __builtin_amdgcn_mfma_f32_16x16x32_bf16(af, bf, acc[ct], 0, 0, 0);
      }
    }

    if (s < 2) {
#pragma unroll
      for (int ct = 0; ct < 4; ct++)
#pragma unroll
        for (int i = 0; i < 4; i++) {
          int row = rh + kq * 4 + i;
          int col = ch + ct * 16 + lrow;
          float v = acc[ct][i] + bb[ct];
          v = v > 0.f ? v : 0.01f * v;
          st2(Xout, row, col * 2, 256, f2bf(v));
        }
      unsigned char* t = Xin; Xin = Xout; Xout = t;
    } else {
#pragma unroll
      for (int ct = 0; ct < 4; ct++) {
        float tv[4];
#pragma unroll
        for (int i = 0; i < 4; i++) tv[i] = acc[ct][i] + bb[ct];
        const int colg = ch + ct * 16 + lrow;
        const int rbase = r0 + rh + kq * 4;
        if (LAST == 0) {
#pragma unroll
          for (int i = 0; i < 4; i++)
            embs_sum[(size_t)(rbase + i) * DN + colg] += tv[i];
          const float S = 1024.f;
          unsigned int pw = pkfp8_4(tv[0] * S, tv[1] * S, tv[2] * S, tv[3] * S);
          const int g = (rbase & 127) >> 4;
          *(unsigned int*)(bt_next + (size_t)colg * NA + (rbase & ~127) +
                           ((g ^ (colg & 7)) << 4) + (rbase & 15)) = pw;
        } else {
#pragma unroll
          for (int i = 0; i < 4; i++) {
            size_t gi = (size_t)(rbase + i) * DN + colg;
            sbf[gi] = f2bf(embs_sum[gi] + tv[i]);
          }
        }
      }
    }
    cw ^= 1;
  }
}

// fused: pre = (users@items^T)*mask; partial[blk] = sum(w*|pre - tq|)
__global__ __launch_bounds__(256) void k_loss(const unsigned short* __restrict__ sbf,
                                              const float* __restrict__ tq,
                                              const float* __restrict__ lw,
                                              const int* __restrict__ msk,
                                              float* __restrict__ partial) {
  const unsigned short* ubf = sbf;
  const unsigned short* ibf = sbf + (size_t)UN * DN;
  const int r0 = blockIdx.x * 32;
  const int c0 = blockIdx.y * 128;
  const int tid = threadIdx.x;
  const int wave = tid >> 6, lane = tid & 63;
  const int wr = (wave >> 1) * 16;
  const int wc = (wave & 1) * 64;
  const int lrow = lane & 15;
  const int kgrp = (lane >> 4) * 8;

  f32x4 acc[4];
#pragma unroll
  for (int i = 0; i < 4; i++) acc[i] = (f32x4){0.f, 0.f, 0.f, 0.f};
#pragma unroll
  for (int kk = 0; kk < 128; kk += 32) {
    bf16x8 af = *(const bf16x8*)(ubf + (size_t)(r0 + wr + lrow) * DN + kk + kgrp);
#pragma unroll
    for (int ct = 0; ct < 4; ct++) {
      bf16x8 bf = *(const bf16x8*)(ibf + (size_t)(c0 + wc + ct * 16 + lrow) * DN + kk + kgrp);
      acc[ct] = __builtin_amdgcn_mfma_f32_16x16x32_bf16(af, bf, acc[ct], 0, 0, 0);
    }
  }
  float lsum = 0.f;
#pragma unroll
  for (int ct = 0; ct < 4; ct++)
#pragma unroll
    for (int i = 0; i < 4; i++) {
      int r = r0 + wr + (lane >> 4) * 4 + i;
      int c = c0 + wc + ct * 16 + lrow;
      size_t gi = (size_t)r * SN + c;
      float pre = msk[gi] ? acc[ct][i] : 0.f;
      lsum += lw[gi] * fabsf(pre - tq[gi]);
    }
  __shared__ float red[256];
  red[tid] = lsum;
  __syncthreads();
  for (int st = 128; st > 0; st >>= 1) {
    if (tid < st) red[tid] += red[tid + st];
    __syncthreads();
  }
  if (tid == 0) partial[blockIdx.x * 64 + blockIdx.y] = red[0];
}

__global__ void k_reduce(const float* __restrict__ p, float* __restrict__ out) {
  __shared__ float red[256];
  float s = 0.f;
  for (int i = threadIdx.x; i < 4096; i += 256) s += p[i];
  red[threadIdx.x] = s;
  __syncthreads();
  for (int st = 128; st > 0; st >>= 1) {
    if (threadIdx.x < st) red[threadIdx.x] += red[threadIdx.x + st];
    __syncthreads();
  }
  if (threadIdx.x == 0) out[0] = red[0];
}

extern "C" void kernel_launch(void* const* d_in, const int* in_sizes, int n_in,
                              void* d_out, int out_size, void* d_ws, size_t ws_size,
                              hipStream_t stream) {
  const float* user_emb = (const float*)d_in[0];
  const float* item_emb = (const float*)d_in[1];
  const float* grpha    = (const float*)d_in[2];
  const float* W1 = (const float*)d_in[3];
  const float* b1 = (const float*)d_in[4];
  const float* W2 = (const float*)d_in[5];
  const float* b2 = (const float*)d_in[6];
  const float* W3 = (const float*)d_in[7];
  const float* b3 = (const float*)d_in[8];
  const float* tq = (const float*)d_in[9];
  const float* lw = (const float*)d_in[10];
  const int* msk  = (const int*)d_in[11];
  float* out = (float*)d_out;

  char* ws = (char*)d_ws;
  unsigned char* A8 = (unsigned char*)ws;        ws += (size_t)NA * NA;              // 105 MB
  float* embs_sum = (float*)ws;                  ws += (size_t)NA * DN * 4;
  unsigned short* part = (unsigned short*)ws;    ws += (size_t)SPLITS * NA * DN * 2; // 21 MB
  unsigned char* Bt8 = (unsigned char*)ws;       ws += (size_t)DN * NA;              // 1.3 MB
  unsigned short* sbf = (unsigned short*)ws;     ws += (size_t)NA * DN * 2;
  unsigned short* wbf = (unsigned short*)ws;     ws += (size_t)3 * DN * DN * 2;
  float* lpart    = (float*)ws;                  ws += 4096 * 4;

  k_prep<<<1624, 256, 0, stream>>>(user_emb, item_emb, W1, W2, W3, embs_sum, wbf, Bt8);
  for (int layer = 0; layer < 3; layer++) {
    if (layer == 0)
      k_gemm<1><<<dim3(SPLITS, NA / 128), 256, 0, stream>>>(grpha, A8, Bt8, part);
    else
      k_gemm<0><<<dim3(SPLITS, NA / 128), 256, 0, stream>>>(grpha, A8, Bt8, part);
    float scale = 1.0f / ((1.0f + (float)layer) * 4194304.0f);  // /(1+l)/4096/1024
    if (layer < 2)
      k_transform<0><<<320, 256, 0, stream>>>(part, scale, wbf, b1, b2, b3,
                                              embs_sum, Bt8, sbf);
    else
      k_transform<1><<<320, 256, 0, stream>>>(part, scale, wbf, b1, b2, b3,
                                              embs_sum, Bt8, sbf);
  }
  k_loss<<<dim3(64, 64), 256, 0, stream>>>(sbf, tq, lw, msk, lpart);
  k_reduce<<<1, 256, 0, stream>>>(lpart, out);
}

// Round 7
// 292.030 us; speedup vs baseline: 1.9582x; 1.0675x over previous
//
#include <hip/hip_runtime.h>
#include <hip/hip_bf16.h>

#define UN 2048
#define SN 8192
#define NA 10240
#define DN 128
#define SPLITS 8
#define KSPL (NA / SPLITS)  // 1280
#define BK 128
#define KT (KSPL / BK)      // 10
#define BM 160              // grid = 8 x 64 = 512 blocks = 2/CU exactly

typedef __attribute__((ext_vector_type(8))) short bf16x8;
typedef __attribute__((ext_vector_type(4))) float f32x4;
typedef __attribute__((ext_vector_type(8))) int i32x8;

#if __has_builtin(__builtin_amdgcn_mfma_scale_f32_16x16x128_f8f6f4)
#define HAVE_MX 1
#else
#define HAVE_MX 0
#endif

__device__ __forceinline__ unsigned short f2bf(float f) {
  unsigned int u = __builtin_bit_cast(unsigned int, f);
  u += 0x7fffu + ((u >> 16) & 1u);
  return (unsigned short)(u >> 16);
}
__device__ __forceinline__ unsigned int pk2(float a, float b) {
  return (unsigned int)f2bf(a) | ((unsigned int)f2bf(b) << 16);
}

// ---- fp8 e4m3fn packing (scaled upstream) ----
#if __has_builtin(__builtin_amdgcn_cvt_pk_fp8_f32)
__device__ __forceinline__ unsigned int pkfp8_4(float a, float b, float c, float d) {
  int w = __builtin_amdgcn_cvt_pk_fp8_f32(a, b, 0, false);
  w = __builtin_amdgcn_cvt_pk_fp8_f32(c, d, w, true);
  return (unsigned int)w;
}
#else
__device__ __forceinline__ unsigned char f2e4m3(float f) {
  unsigned int u = __builtin_bit_cast(unsigned int, f);
  unsigned int s = (u >> 24) & 0x80u;
  unsigned int a = u & 0x7fffffffu;
  if (a < 0x3c800000u) return (unsigned char)s;
  if (a > 0x43e00000u) a = 0x43e00000u;
  a += 0x7ffffu + ((a >> 20) & 1u);
  unsigned int e = (a >> 23) - 120u;
  unsigned int m = (a >> 20) & 7u;
  if (e > 15u) { e = 15u; m = 6u; }
  return (unsigned char)(s | (e << 3) | m);
}
__device__ __forceinline__ unsigned int pkfp8_4(float a, float b, float c, float d) {
  return (unsigned int)f2e4m3(a) | ((unsigned int)f2e4m3(b) << 8) |
         ((unsigned int)f2e4m3(c) << 16) | ((unsigned int)f2e4m3(d) << 24);
}
#endif

// async global->LDS, 16B per lane
__device__ __forceinline__ void gl_lds16(const void* g, void* l) {
  __builtin_amdgcn_global_load_lds((const __attribute__((address_space(1))) unsigned int*)g,
                                   (__attribute__((address_space(3))) unsigned int*)l, 16, 0, 0);
}
// swizzled LDS helpers (bf16 tiles in k_transform)
__device__ __forceinline__ void st16(unsigned char* base, int row, int cb, int stride, uint4 v) {
  int off = row * stride + cb;
  off ^= (row & 7) << 4;
  *(uint4*)(base + off) = v;
}
__device__ __forceinline__ bf16x8 ld16(const unsigned char* base, int row, int cb, int stride) {
  int off = row * stride + cb;
  off ^= (row & 7) << 4;
  return *(const bf16x8*)(base + off);
}
__device__ __forceinline__ void st2(unsigned char* base, int row, int cb, int stride, unsigned short h) {
  int off = row * stride + cb;
  off ^= (row & 7) << 4;
  *(unsigned short*)(base + off) = h;
}

// prep (fused, block-ranged):
//  [0,25600)        grpha fp32 -> A8 fp8 (x4096), permuted image
//  [25600,26880)    embs_sum = concat(ue,ie)
//  [26880,26904)    W1..3 -> wbf bf16 pre-swizzled
//  [26904,27224)    Bt8 layer-0 from ue/ie (x1024)
// fp8 image: in each 128-k block of row r, granule g (16 k) at byte pos (g^(r&7))*16.
__global__ void k_prep(const float* __restrict__ grpha,
                       const float* __restrict__ ue, const float* __restrict__ ie,
                       const float* __restrict__ W1, const float* __restrict__ W2,
                       const float* __restrict__ W3, unsigned char* __restrict__ A8,
                       float* __restrict__ es, unsigned short* __restrict__ wbf,
                       unsigned char* __restrict__ bt) {
  const int bid = blockIdx.x;
  const int tid = threadIdx.x;
  if (bid < 25600) {
    size_t gid = (size_t)bid * 256 + tid;  // 6,553,600 granules of 16
    int r = (int)(gid / 640);
    int w = (int)(gid % 640);
    int s = w >> 3, g = w & 7;
    const float* p1 = grpha + (size_t)r * NA + s * 128 + g * 16;
    float4 f0 = *(const float4*)p1;
    float4 f1 = *(const float4*)(p1 + 4);
    float4 f2 = *(const float4*)(p1 + 8);
    float4 f3 = *(const float4*)(p1 + 12);
    const float S = 4096.f;
    uint4 o;
    o.x = pkfp8_4(f0.x * S, f0.y * S, f0.z * S, f0.w * S);
    o.y = pkfp8_4(f1.x * S, f1.y * S, f1.z * S, f1.w * S);
    o.z = pkfp8_4(f2.x * S, f2.y * S, f2.z * S, f2.w * S);
    o.w = pkfp8_4(f3.x * S, f3.y * S, f3.z * S, f3.w * S);
    *(uint4*)(A8 + (size_t)r * NA + s * 128 + ((g ^ (r & 7)) * 16)) = o;
  } else if (bid < 26880) {
    int i = (bid - 25600) * 256 + tid;  // float4 over NA*DN/4
    float4 v = (i < UN * DN / 4) ? ((const float4*)ue)[i] : ((const float4*)ie)[i - UN * DN / 4];
    ((float4*)es)[i] = v;
  } else if (bid < 26904) {
    int g = (bid - 26880) * 256 + tid;  // 6144
    int mat = g / 2048;
    int idx = g % 2048;
    int r = idx / 16, cg = idx % 16;
    const float* Wp = (mat == 0) ? W1 : (mat == 1) ? W2 : W3;
    const float4* src = (const float4*)(Wp + (size_t)r * DN + cg * 8);
    float4 a = src[0], b = src[1];
    uint4 w;
    w.x = pk2(a.x, a.y); w.y = pk2(a.z, a.w);
    w.z = pk2(b.x, b.y); w.w = pk2(b.z, b.w);
    *(uint4*)(wbf + (size_t)mat * 16384 + r * 128 + ((cg ^ (r & 7)) * 8)) = w;
  } else {
    int t = (bid - 26904) * 256 + tid;  // 81920 granules
    int c = t & 127;
    int w = t >> 7;
    int kb = w >> 3, g = w & 7;
    const int kbase = kb * 128 + g * 16;
    float v[16];
#pragma unroll
    for (int j = 0; j < 16; j++) {
      int r = kbase + j;
      v[j] = (r < UN) ? ue[(size_t)r * DN + c] : ie[(size_t)(r - UN) * DN + c];
    }
    const float S = 1024.f;
    uint4 o;
    o.x = pkfp8_4(v[0] * S, v[1] * S, v[2] * S, v[3] * S);
    o.y = pkfp8_4(v[4] * S, v[5] * S, v[6] * S, v[7] * S);
    o.z = pkfp8_4(v[8] * S, v[9] * S, v[10] * S, v[11] * S);
    o.w = pkfp8_4(v[12] * S, v[13] * S, v[14] * S, v[15] * S);
    *(uint4*)(bt + (size_t)c * NA + kb * 128 + ((g ^ (c & 7)) * 16)) = o;
  }
}

// part[ks] = A8[m0:m0+160, ks-chunk] @ Bt8[ks-chunk]^T  (fp8 MX MFMA K=128)
// T4 counted-vmcnt double-buffer; BM=160 -> 512 blocks, full residency.
__global__ __launch_bounds__(256, 2) void k_gemm(const unsigned char* __restrict__ A8,
                                                 const unsigned char* __restrict__ B8,
                                                 unsigned short* __restrict__ part) {
  __shared__ __align__(16) unsigned char As[2][BM * 128];   // 2 x 20 KB
  __shared__ __align__(16) unsigned char Bs[2][128 * 128];  // 2 x 16 KB
  const int ks = blockIdx.x;
  const int m0 = blockIdx.y * BM;
  const int k0 = ks * KSPL;
  const int tid = threadIdx.x;
  const int wave = tid >> 6, lane = tid & 63;
  const int lrow = lane & 15;
  const int kq = lane >> 4;          // 0..3
  const int wr = (wave >> 1) * 80;   // wave row base (0 / 80)
  const int wc = (wave & 1) * 64;    // wave col base
  const int rx = lrow & 7;           // fragment-row swizzle key

  auto stage = [&](int buf, int kt) {
    const int kg = k0 + kt * BK;
#pragma unroll
    for (int j = 0; j < 4; j++) {
      const int L = j * 256 + tid;   // B granule 0..1023
      const int row = L >> 3, p = L & 7;
      gl_lds16(B8 + (size_t)row * NA + kg + p * 16, (char*)Bs[buf] + L * 16);
    }
#pragma unroll
    for (int j = 0; j < 5; j++) {
      const int L = j * 256 + tid;   // A granule 0..1279
      const int row = L >> 3, p = L & 7;
      gl_lds16(A8 + (size_t)(m0 + row) * NA + kg + p * 16, (char*)As[buf] + L * 16);
    }
  };

  f32x4 acc[4][5];  // [fj][fi]
#pragma unroll
  for (int fj = 0; fj < 4; fj++)
#pragma unroll
    for (int fi = 0; fi < 5; fi++) acc[fj][fi] = (f32x4){0.f, 0.f, 0.f, 0.f};

  stage(0, 0);
  int cur = 0;
  for (int kt = 0; kt < KT; kt++) {
    // barrier A: all waves done reading buf[cur^1] -> safe to overwrite
    __builtin_amdgcn_s_barrier();
    if (kt + 1 < KT) {
      stage(cur ^ 1, kt + 1);                      // issue next tile (9 loads)
      asm volatile("s_waitcnt vmcnt(9)" ::: "memory");  // wait only stage(kt)
    } else {
      asm volatile("s_waitcnt vmcnt(0)" ::: "memory");
    }
    __builtin_amdgcn_s_barrier();  // all waves' stage(kt) writes visible

#if HAVE_MX
    i32x8 av[5], bv[4];
#pragma unroll
    for (int fi = 0; fi < 5; fi++) {
      const unsigned char* ab = As[cur] + (wr + fi * 16 + lrow) * 128;
      uint4 lo = *(const uint4*)(ab + (((2 * kq) ^ rx) << 4));
      uint4 hi = *(const uint4*)(ab + (((2 * kq + 1) ^ rx) << 4));
      i32x8 a; a[0] = lo.x; a[1] = lo.y; a[2] = lo.z; a[3] = lo.w;
      a[4] = hi.x; a[5] = hi.y; a[6] = hi.z; a[7] = hi.w;
      av[fi] = a;
    }
#pragma unroll
    for (int fj = 0; fj < 4; fj++) {
      const unsigned char* bb = Bs[cur] + (wc + fj * 16 + lrow) * 128;
      uint4 lo = *(const uint4*)(bb + (((2 * kq) ^ rx) << 4));
      uint4 hi = *(const uint4*)(bb + (((2 * kq + 1) ^ rx) << 4));
      i32x8 b; b[0] = lo.x; b[1] = lo.y; b[2] = lo.z; b[3] = lo.w;
      b[4] = hi.x; b[5] = hi.y; b[6] = hi.z; b[7] = hi.w;
      bv[fj] = b;
    }
#pragma unroll
    for (int fj = 0; fj < 4; fj++)
#pragma unroll
      for (int fi = 0; fi < 5; fi++)
        acc[fj][fi] = __builtin_amdgcn_mfma_scale_f32_16x16x128_f8f6f4(
            bv[fj], av[fi], acc[fj][fi], 0, 0, 0, 0x7f7f7f7f, 0, 0x7f7f7f7f);
#else
#pragma unroll
    for (int s = 0; s < 4; s++) {
      const int G = 2 * s + (kq >> 1);
      const int boff = ((G ^ rx) << 4) + (kq & 1) * 8;
      long a[5], b[4];
#pragma unroll
      for (int fi = 0; fi < 5; fi++)
        a[fi] = *(const long*)(As[cur] + (wr + fi * 16 + lrow) * 128 + boff);
#pragma unroll
      for (int fj = 0; fj < 4; fj++)
        b[fj] = *(const long*)(Bs[cur] + (wc + fj * 16 + lrow) * 128 + boff);
#pragma unroll
      for (int fj = 0; fj < 4; fj++)
#pragma unroll
        for (int fi = 0; fi < 5; fi++)
          acc[fj][fi] = __builtin_amdgcn_mfma_f32_16x16x32_fp8_fp8(b[fj], a[fi], acc[fj][fi], 0, 0, 0);
    }
#endif
    cur ^= 1;
  }

  // operand-swapped D: lane holds 4 consecutive n at row m
  unsigned short* op = part + (size_t)ks * NA * DN;
#pragma unroll
  for (int fi = 0; fi < 5; fi++) {
    const size_t mrow = (size_t)(m0 + wr + fi * 16 + lrow) * DN;
#pragma unroll
    for (int fj = 0; fj < 4; fj++) {
      const int n = wc + fj * 16 + kq * 4;
      uint2 pkd;
      pkd.x = pk2(acc[fj][fi][0], acc[fj][fi][1]);
      pkd.y = pk2(acc[fj][fi][2], acc[fj][fi][3]);
      *(uint2*)(op + mrow + n) = pkd;
    }
  }
}

// x = (sum of SPLITS bf16 partials)*scale; 3-layer MLP.
// LAST=0: embs_sum += x, write Bt8 image for next layer.
// LAST=1: sbf = bf16(embs_sum + x)
template <int LAST>
__global__ __launch_bounds__(256) void k_transform(
    const unsigned short* __restrict__ part, float scale,
    const unsigned short* __restrict__ wbf,
    const float* __restrict__ b1, const float* __restrict__ b2, const float* __restrict__ b3,
    float* __restrict__ embs_sum, unsigned char* __restrict__ bt_next,
    unsigned short* __restrict__ sbf) {
  __shared__ __align__(16) unsigned char Ws[2][128 * 128 * 2];  // 2 x 32 KB
  __shared__ __align__(16) unsigned char Xa[32 * 128 * 2];      // 8 KB
  __shared__ __align__(16) unsigned char Xb[32 * 128 * 2];      // 8 KB
  const int r0 = blockIdx.x * 32;
  const int tid = threadIdx.x;
  const int wave = tid >> 6, lane = tid & 63;
  const int lrow = lane & 15;
  const int kq = lane >> 4;
  const int kgrp = kq * 8;
  const int rh = (wave & 1) * 16;
  const int ch = (wave >> 1) * 64;

  auto stage_W = [&](int buf, int s) {
#pragma unroll
    for (int j = 0; j < 8; j++) {
      const int L = j * 256 + tid;
      gl_lds16(wbf + (size_t)s * 16384 + L * 8, (char*)Ws[buf] + L * 16);
    }
  };

  stage_W(0, 0);
  {  // stage input tile into Xa: sum 8 bf16 slabs -> fp32 -> scale -> bf16
    const int xr = tid >> 3, xc = (tid & 7) * 16;
    const size_t base = (size_t)(r0 + xr) * DN + xc;
    float xs[16];
#pragma unroll
    for (int q = 0; q < 16; q++) xs[q] = 0.f;
#pragma unroll
    for (int s = 0; s < SPLITS; s++) {
      const unsigned short* p = part + (size_t)s * NA * DN + base;
      uint4 w1 = *(const uint4*)p;
      uint4 w2 = *(const uint4*)(p + 8);
      const unsigned int wsv[8] = {w1.x, w1.y, w1.z, w1.w, w2.x, w2.y, w2.z, w2.w};
#pragma unroll
      for (int q = 0; q < 8; q++) {
        xs[2 * q]     += __builtin_bit_cast(float, wsv[q] << 16);
        xs[2 * q + 1] += __builtin_bit_cast(float, wsv[q] & 0xffff0000u);
      }
    }
    uint4 w;
    w.x = pk2(xs[0] * scale, xs[1] * scale);   w.y = pk2(xs[2] * scale, xs[3] * scale);
    w.z = pk2(xs[4] * scale, xs[5] * scale);   w.w = pk2(xs[6] * scale, xs[7] * scale);
    st16(Xa, xr, xc * 2, 256, w);
    w.x = pk2(xs[8] * scale, xs[9] * scale);   w.y = pk2(xs[10] * scale, xs[11] * scale);
    w.z = pk2(xs[12] * scale, xs[13] * scale); w.w = pk2(xs[14] * scale, xs[15] * scale);
    st16(Xa, xr, (xc + 8) * 2, 256, w);
  }

  const float* bp[3] = {b1, b2, b3};
  unsigned char* Xin = Xa;
  unsigned char* Xout = Xb;
  int cw = 0;

  for (int s = 0; s < 3; s++) {
    __syncthreads();
    if (s < 2) stage_W(cw ^ 1, s + 1);
    float bb[4];
#pragma unroll
    for (int ct = 0; ct < 4; ct++) bb[ct] = bp[s][ch + ct * 16 + lrow];

    f32x4 acc[4];
#pragma unroll
    for (int i = 0; i < 4; i++) acc[i] = (f32x4){0.f, 0.f, 0.f, 0.f};
#pragma unroll
    for (int kk = 0; kk < 128; kk += 32) {
      bf16x8 af = ld16(Xin, rh + lrow, (kk + kgrp) * 2, 256);
#pragma unroll
      for (int ct = 0; ct < 4; ct++) {
        bf16x8 bf = ld16(Ws[cw], ch + ct * 16 + lrow, (kk + kgrp) * 2, 256);
        acc[ct] = __builtin_amdgcn_mfma_f32_16x16x32_bf16(af, bf, acc[ct], 0, 0, 0);
      }
    }

    if (s < 2) {
#pragma unroll
      for (int ct = 0; ct < 4; ct++)
#pragma unroll
        for (int i = 0; i < 4; i++) {
          int row = rh + kq * 4 + i;
          int col = ch + ct * 16 + lrow;
          float v = acc[ct][i] + bb[ct];
          v = v > 0.f ? v : 0.01f * v;
          st2(Xout, row, col * 2, 256, f2bf(v));
        }
      unsigned char* t = Xin; Xin = Xout; Xout = t;
    } else {
#pragma unroll
      for (int ct = 0; ct < 4; ct++) {
        float tv[4];
#pragma unroll
        for (int i = 0; i < 4; i++) tv[i] = acc[ct][i] + bb[ct];
        const int colg = ch + ct * 16 + lrow;
        const int rbase = r0 + rh + kq * 4;
        if (LAST == 0) {
#pragma unroll
          for (int i = 0; i < 4; i++)
            embs_sum[(size_t)(rbase + i) * DN + colg] += tv[i];
          const float S = 1024.f;
          unsigned int pw = pkfp8_4(tv[0] * S, tv[1] * S, tv[2] * S, tv[3] * S);
          const int g = (rbase & 127) >> 4;
          *(unsigned int*)(bt_next + (size_t)colg * NA + (rbase & ~127) +
                           ((g ^ (colg & 7)) << 4) + (rbase & 15)) = pw;
        } else {
#pragma unroll
          for (int i = 0; i < 4; i++) {
            size_t gi = (size_t)(rbase + i) * DN + colg;
            sbf[gi] = f2bf(embs_sum[gi] + tv[i]);
          }
        }
      }
    }
    cw ^= 1;
  }
}

// fused: pre = (users@items^T)*mask; partial[blk] = sum(w*|pre - tq|)
__global__ __launch_bounds__(256) void k_loss(const unsigned short* __restrict__ sbf,
                                              const float* __restrict__ tq,
                                              const float* __restrict__ lw,
                                              const int* __restrict__ msk,
                                              float* __restrict__ partial) {
  const unsigned short* ubf = sbf;
  const unsigned short* ibf = sbf + (size_t)UN * DN;
  const int r0 = blockIdx.x * 32;
  const int c0 = blockIdx.y * 128;
  const int tid = threadIdx.x;
  const int wave = tid >> 6, lane = tid & 63;
  const int wr = (wave >> 1) * 16;
  const int wc = (wave & 1) * 64;
  const int lrow = lane & 15;
  const int kgrp = (lane >> 4) * 8;

  f32x4 acc[4];
#pragma unroll
  for (int i = 0; i < 4; i++) acc[i] = (f32x4){0.f, 0.f, 0.f, 0.f};
#pragma unroll
  for (int kk = 0; kk < 128; kk += 32) {
    bf16x8 af = *(const bf16x8*)(ubf + (size_t)(r0 + wr + lrow) * DN + kk + kgrp);
#pragma unroll
    for (int ct = 0; ct < 4; ct++) {
      bf16x8 bf = *(const bf16x8*)(ibf + (size_t)(c0 + wc + ct * 16 + lrow) * DN + kk + kgrp);
      acc[ct] = __builtin_amdgcn_mfma_f32_16x16x32_bf16(af, bf, acc[ct], 0, 0, 0);
    }
  }
  float lsum = 0.f;
#pragma unroll
  for (int ct = 0; ct < 4; ct++)
#pragma unroll
    for (int i = 0; i < 4; i++) {
      int r = r0 + wr + (lane >> 4) * 4 + i;
      int c = c0 + wc + ct * 16 + lrow;
      size_t gi = (size_t)r * SN + c;
      float pre = msk[gi] ? acc[ct][i] : 0.f;
      lsum += lw[gi] * fabsf(pre - tq[gi]);
    }
  __shared__ float red[256];
  red[tid] = lsum;
  __syncthreads();
  for (int st = 128; st > 0; st >>= 1) {
    if (tid < st) red[tid] += red[tid + st];
    __syncthreads();
  }
  if (tid == 0) partial[blockIdx.x * 64 + blockIdx.y] = red[0];
}

__global__ void k_reduce(const float* __restrict__ p, float* __restrict__ out) {
  __shared__ float red[256];
  float s = 0.f;
  for (int i = threadIdx.x; i < 4096; i += 256) s += p[i];
  red[threadIdx.x] = s;
  __syncthreads();
  for (int st = 128; st > 0; st >>= 1) {
    if (threadIdx.x < st) red[threadIdx.x] += red[threadIdx.x + st];
    __syncthreads();
  }
  if (threadIdx.x == 0) out[0] = red[0];
}

extern "C" void kernel_launch(void* const* d_in, const int* in_sizes, int n_in,
                              void* d_out, int out_size, void* d_ws, size_t ws_size,
                              hipStream_t stream) {
  const float* user_emb = (const float*)d_in[0];
  const float* item_emb = (const float*)d_in[1];
  const float* grpha    = (const float*)d_in[2];
  const float* W1 = (const float*)d_in[3];
  const float* b1 = (const float*)d_in[4];
  const float* W2 = (const float*)d_in[5];
  const float* b2 = (const float*)d_in[6];
  const float* W3 = (const float*)d_in[7];
  const float* b3 = (const float*)d_in[8];
  const float* tq = (const float*)d_in[9];
  const float* lw = (const float*)d_in[10];
  const int* msk  = (const int*)d_in[11];
  float* out = (float*)d_out;

  char* ws = (char*)d_ws;
  unsigned char* A8 = (unsigned char*)ws;        ws += (size_t)NA * NA;              // 105 MB
  float* embs_sum = (float*)ws;                  ws += (size_t)NA * DN * 4;
  unsigned short* part = (unsigned short*)ws;    ws += (size_t)SPLITS * NA * DN * 2; // 21 MB
  unsigned char* Bt8 = (unsigned char*)ws;       ws += (size_t)DN * NA;              // 1.3 MB
  unsigned short* sbf = (unsigned short*)ws;     ws += (size_t)NA * DN * 2;
  unsigned short* wbf = (unsigned short*)ws;     ws += (size_t)3 * DN * DN * 2;
  float* lpart    = (float*)ws;                  ws += 4096 * 4;

  k_prep<<<27224, 256, 0, stream>>>(grpha, user_emb, item_emb, W1, W2, W3,
                                    A8, embs_sum, wbf, Bt8);
  for (int layer = 0; layer < 3; layer++) {
    k_gemm<<<dim3(SPLITS, NA / BM), 256, 0, stream>>>(A8, Bt8, part);
    float scale = 1.0f / ((1.0f + (float)layer) * 4194304.0f);  // /(1+l)/4096/1024
    if (layer < 2)
      k_transform<0><<<320, 256, 0, stream>>>(part, scale, wbf, b1, b2, b3,
                                              embs_sum, Bt8, sbf);
    else
      k_transform<1><<<320, 256, 0, stream>>>(part, scale, wbf, b1, b2, b3,
                                              embs_sum, Bt8, sbf);
  }
  k_loss<<<dim3(64, 64), 256, 0, stream>>>(sbf, tq, lw, msk, lpart);
  k_reduce<<<1, 256, 0, stream>>>(lpart, out);
}